// Round 1
// baseline (3004.050 us; speedup 1.0000x reference)
//
#include <hip/hip_runtime.h>
#include <math.h>

// ---------------- problem constants ----------------
#define BB    2
#define TT    4096
#define CDIM  2048
#define NHQ   16
#define NKV   4
#define HD    128
#define HALF  64
#define NREP  4
#define RBLK  16
#define NB    256
#define TOPK  64

#define QSZ ((size_t)BB * TT * NHQ * HD)   // 16,777,216 floats
#define KSZ ((size_t)BB * TT * NKV * HD)   //  4,194,304 floats
#define CSZ ((size_t)BB * NKV * TOPK * HD) //     65,536 floats

// ---------------- fp32 tiled GEMM: C[M,N] = A[M,K] @ W[K,N] ----------------
#define GBM 128
#define GBN 128
#define GBK 8
#define GTM 8
#define GTN 8

__global__ __launch_bounds__(256) void csa_sgemm(const float* __restrict__ A,
                                                 const float* __restrict__ W,
                                                 float* __restrict__ C,
                                                 int M, int N, int K) {
  __shared__ float As[GBK][GBM];
  __shared__ float Bs[GBK][GBN];
  const int tid = threadIdx.x;
  const int bm = blockIdx.y * GBM;
  const int bn = blockIdx.x * GBN;
  const int arow = tid >> 1;          // 0..127
  const int acol = (tid & 1) << 2;    // 0 or 4
  const int brow = tid >> 5;          // 0..7
  const int bcol = (tid & 31) << 2;   // 0..124
  const int tm = (tid >> 4) * GTM;    // 0..120
  const int tn = (tid & 15) * GTN;    // 0..120

  float acc[GTM][GTN];
#pragma unroll
  for (int i = 0; i < GTM; ++i)
#pragma unroll
    for (int j = 0; j < GTN; ++j) acc[i][j] = 0.f;

  for (int k0 = 0; k0 < K; k0 += GBK) {
    float4 av = *(const float4*)(A + (size_t)(bm + arow) * K + k0 + acol);
    float4 bv = *(const float4*)(W + (size_t)(k0 + brow) * N + bn + bcol);
    __syncthreads();
    As[acol + 0][arow] = av.x;
    As[acol + 1][arow] = av.y;
    As[acol + 2][arow] = av.z;
    As[acol + 3][arow] = av.w;
    *(float4*)(&Bs[brow][bcol]) = bv;
    __syncthreads();
#pragma unroll
    for (int kk = 0; kk < GBK; ++kk) {
      float af[GTM], bf[GTN];
      *(float4*)&af[0] = *(const float4*)&As[kk][tm];
      *(float4*)&af[4] = *(const float4*)&As[kk][tm + 4];
      *(float4*)&bf[0] = *(const float4*)&Bs[kk][tn];
      *(float4*)&bf[4] = *(const float4*)&Bs[kk][tn + 4];
#pragma unroll
      for (int i = 0; i < GTM; ++i)
#pragma unroll
        for (int j = 0; j < GTN; ++j) acc[i][j] += af[i] * bf[j];
    }
  }
#pragma unroll
  for (int i = 0; i < GTM; ++i) {
    float* crow = C + (size_t)(bm + tm + i) * N + bn + tn;
    *(float4*)crow       = make_float4(acc[i][0], acc[i][1], acc[i][2], acc[i][3]);
    *(float4*)(crow + 4) = make_float4(acc[i][4], acc[i][5], acc[i][6], acc[i][7]);
  }
}

// ---------------- RoPE table (f64 math once) ----------------
__global__ void csa_rope_table(float* __restrict__ cost, float* __restrict__ sint) {
  int idx = blockIdx.x * blockDim.x + threadIdx.x;
  if (idx >= TT * HALF) return;
  int t = idx / HALF, i = idx % HALF;
  double freq = pow(10000.0, -(double)i / (double)HALF);
  double ang = (double)t * freq;
  cost[idx] = (float)cos(ang);
  sint[idx] = (float)sin(ang);
}

// ---------------- RoPE apply in place, buf is (B,T,nh,HD) ----------------
__global__ void csa_rope_apply(float* __restrict__ buf, const float* __restrict__ cost,
                               const float* __restrict__ sint, int nheads, int total) {
  int idx = blockIdx.x * blockDim.x + threadIdx.x;
  if (idx >= total) return;
  int i = idx % HALF;
  int h = (idx / HALF) % nheads;
  int t = (idx / (HALF * nheads)) % TT;
  int b = idx / (HALF * nheads * TT);
  float c = cost[t * HALF + i], s = sint[t * HALF + i];
  float* p = buf + ((((size_t)b * TT + t) * nheads + h) * HD) + 2 * i;
  float a = p[0], q = p[1];
  p[0] = a * c - q * s;
  p[1] = a * s + q * c;
}

// ---------------- partial column sums of x over T (for ki_mean) ----------------
__global__ void csa_xpart(const float* __restrict__ x, float* __restrict__ xpart) {
  int d = blockIdx.x * 256 + threadIdx.x;  // 0..2047
  int ts = blockIdx.y;                     // 0..15
  int b = blockIdx.z;
  float s = 0.f;
  int t0 = ts * (TT / 16);
  for (int t = t0; t < t0 + TT / 16; ++t) s += x[((size_t)b * TT + t) * CDIM + d];
  xpart[((size_t)b * 16 + ts) * CDIM + d] = s;
}

// ---------------- ki_mean[b,j] = (mean_t x[b]) @ wik ----------------
__global__ void csa_kimean(const float* __restrict__ xpart, const float* __restrict__ wik,
                           float* __restrict__ ki) {
  int b = blockIdx.x >> 7;
  int j = blockIdx.x & 127;
  int tid = threadIdx.x;
  float s = 0.f;
  for (int d = tid; d < CDIM; d += 256) {
    float xm = 0.f;
#pragma unroll
    for (int ts = 0; ts < 16; ++ts) xm += xpart[((size_t)b * 16 + ts) * CDIM + d];
    s += xm * wik[(size_t)d * HD + j];
  }
  __shared__ float red[256];
  red[tid] = s;
  __syncthreads();
  for (int off = 128; off > 0; off >>= 1) {
    if (tid < off) red[tid] += red[tid + off];
    __syncthreads();
  }
  if (tid == 0) ki[b * HD + j] = red[0] * (1.f / (float)TT);
}

// ---------------- u[b,d] = wiq[d,:] . ki[b,:] ----------------
__global__ void csa_u(const float* __restrict__ wiq, const float* __restrict__ ki,
                      float* __restrict__ u) {
  int idx = blockIdx.x * 256 + threadIdx.x;  // B*DIM
  int b = idx / CDIM, d = idx % CDIM;
  float s = 0.f;
#pragma unroll 8
  for (int j = 0; j < HD; ++j) s += wiq[(size_t)d * HD + j] * ki[b * HD + j];
  u[idx] = s;
}

// ---------------- scores[b,t] = x[b,t,:] . u[b,:]  (t < NB) ----------------
__global__ void csa_scores(const float* __restrict__ x, const float* __restrict__ u,
                           float* __restrict__ sc) {
  int b = blockIdx.x >> 8;
  int t = blockIdx.x & 255;
  int tid = threadIdx.x;
  float s = 0.f;
  for (int d = tid; d < CDIM; d += 256)
    s += x[((size_t)b * TT + t) * CDIM + d] * u[b * CDIM + d];
  __shared__ float red[256];
  red[tid] = s;
  __syncthreads();
  for (int off = 128; off > 0; off >>= 1) {
    if (tid < off) red[tid] += red[tid + off];
    __syncthreads();
  }
  if (tid == 0) sc[blockIdx.x] = red[0];
}

// ---------------- per-batch top-64 of 256 scores (set only matters) ----------------
__global__ void csa_topk(const float* __restrict__ sc, int* __restrict__ topk) {
  __shared__ float val[NB];
  __shared__ float rv[256];
  __shared__ int ri[256];
  int b = blockIdx.x, tid = threadIdx.x;
  val[tid] = sc[b * NB + tid];
  __syncthreads();
  for (int it = 0; it < TOPK; ++it) {
    rv[tid] = val[tid];
    ri[tid] = tid;
    __syncthreads();
    for (int off = 128; off > 0; off >>= 1) {
      if (tid < off) {
        if (rv[tid + off] > rv[tid] ||
            (rv[tid + off] == rv[tid] && ri[tid + off] < ri[tid])) {
          rv[tid] = rv[tid + off];
          ri[tid] = ri[tid + off];
        }
      }
      __syncthreads();
    }
    if (tid == 0) {
      topk[b * TOPK + it] = ri[0];
      val[ri[0]] = -INFINITY;
    }
    __syncthreads();
  }
}

// ---------------- compress only selected blocks: ck/cv (B,NKV,TOPK,HD) ----------------
__global__ __launch_bounds__(64) void csa_compress(const float* __restrict__ kbuf,
                                                   const float* __restrict__ vbuf,
                                                   const int* __restrict__ topk,
                                                   const float* __restrict__ cwa,
                                                   const float* __restrict__ cwb,
                                                   float* __restrict__ ck,
                                                   float* __restrict__ cv) {
  int blk = blockIdx.x;                 // B*NKV*TOPK
  int b = blk / (NKV * TOPK);
  int h = (blk / TOPK) % NKV;
  int j = blk % TOPK;
  int n = topk[b * TOPK + j];
  int l = threadIdx.x;                  // 0..63
  float ca0 = cwa[l], ca1 = cwa[l + 64];
  float cb0 = cwb[l], cb1 = cwb[l + 64];
  float kk[RBLK][2], vv[RBLK][2], ar[RBLK], br[RBLK];
#pragma unroll
  for (int r = 0; r < RBLK; ++r) {
    int t = n * RBLK + r;
    size_t base = (((size_t)b * TT + t) * NKV + h) * HD;
    kk[r][0] = kbuf[base + l];
    kk[r][1] = kbuf[base + l + 64];
    vv[r][0] = vbuf[base + l];
    vv[r][1] = vbuf[base + l + 64];
    float pa = kk[r][0] * ca0 + kk[r][1] * ca1;
    float pb = kk[r][0] * cb0 + kk[r][1] * cb1;
    for (int off = 32; off > 0; off >>= 1) {
      pa += __shfl_xor(pa, off);
      pb += __shfl_xor(pb, off);
    }
    ar[r] = pa;
    br[r] = pb;
  }
  float ma = -INFINITY, mb = -INFINITY;
#pragma unroll
  for (int r = 0; r < RBLK; ++r) { ma = fmaxf(ma, ar[r]); mb = fmaxf(mb, br[r]); }
  float ea[RBLK], eb[RBLK], sa = 0.f, sb = 0.f;
#pragma unroll
  for (int r = 0; r < RBLK; ++r) {
    ea[r] = expf(ar[r] - ma); sa += ea[r];
    eb[r] = expf(br[r] - mb); sb += eb[r];
  }
  float isa = 1.f / sa, isb = 1.f / sb;
  float o0 = 0.f, o1 = 0.f, p0 = 0.f, p1 = 0.f;
#pragma unroll
  for (int r = 0; r < RBLK; ++r) {
    float w = 0.5f * (ea[r] * isa + eb[r] * isb);
    o0 += w * kk[r][0]; o1 += w * kk[r][1];
    p0 += w * vv[r][0]; p1 += w * vv[r][1];
  }
  size_t cb_ = (((size_t)b * NKV + h) * TOPK + j) * HD;
  ck[cb_ + l] = o0; ck[cb_ + l + 64] = o1;
  cv[cb_ + l] = p0; cv[cb_ + l + 64] = p1;
}

// ---------------- attention over 64 compressed keys; writes over q buffer ----------------
#define ATQ 256
__global__ __launch_bounds__(256) void csa_attn(float* __restrict__ qbuf,   // in: q, out: att
                                                const float* __restrict__ ck,
                                                const float* __restrict__ cv) {
  __shared__ float ckL[TOPK][HD];  // XOR-swizzled: [j][d ^ (j&31)]
  __shared__ float cvL[TOPK][HD];
  const int tid = threadIdx.x;
  const int b = blockIdx.y / NHQ;
  const int h = blockIdx.y % NHQ;
  const int kvh = h >> 2;  // NREP = 4
  const int tq0 = blockIdx.x * ATQ;
  const size_t cbase = ((size_t)(b * NKV + kvh) * TOPK) * HD;
  for (int idx = tid; idx < TOPK * HD; idx += 256) {
    int j = idx >> 7, d = idx & 127;
    int dp = (d & 96) | ((d ^ (j & 31)) & 31);
    ckL[j][dp] = ck[cbase + idx];
    cvL[j][dp] = cv[cbase + idx];
  }
  __syncthreads();
  const int w = tid >> 6, l = tid & 63;
  const int lsw = l & 31;
  const float scale = 0.08838834764831845f;  // 1/sqrt(128)
  for (int qi = 0; qi < ATQ / 4; ++qi) {
    int t = tq0 + w * (ATQ / 4) + qi;
    size_t qbase = (((size_t)b * TT + t) * NHQ + h) * HD;
    float q0 = qbuf[qbase + l];
    float q1 = qbuf[qbase + l + 64];
    // logits: lane l = key j
    float s = 0.f;
#pragma unroll 16
    for (int d = 0; d < 64; ++d)
      s += __shfl(q0, d) * ckL[l][(d & 96) | ((d ^ lsw) & 31)];
#pragma unroll 16
    for (int d = 64; d < 128; ++d)
      s += __shfl(q1, d - 64) * ckL[l][(d & 96) | ((d ^ lsw) & 31)];
    s *= scale;
    float m = s;
    for (int off = 32; off > 0; off >>= 1) m = fmaxf(m, __shfl_xor(m, off));
    float e = expf(s - m);
    float sum = e;
    for (int off = 32; off > 0; off >>= 1) sum += __shfl_xor(sum, off);
    float p = e / sum;
    // output: lane l = dims l, l+64
    float o0 = 0.f, o1 = 0.f;
#pragma unroll 16
    for (int j = 0; j < TOPK; ++j) {
      float pj = __shfl(p, j);
      int jsw = j & 31;
      o0 += pj * cvL[j][(l ^ jsw) & 31 | (l & 96)];
      o1 += pj * cvL[j][(((l + 64) ^ jsw) & 31) | ((l + 64) & 96)];
    }
    qbuf[qbase + l] = o0;
    qbuf[qbase + l + 64] = o1;
  }
}

// ---------------- launch ----------------
extern "C" void kernel_launch(void* const* d_in, const int* in_sizes, int n_in,
                              void* d_out, int out_size, void* d_ws, size_t ws_size,
                              hipStream_t stream) {
  const float* x   = (const float*)d_in[0];
  const float* wq  = (const float*)d_in[1];
  const float* wk  = (const float*)d_in[2];
  const float* wv  = (const float*)d_in[3];
  const float* wo  = (const float*)d_in[4];
  const float* wiq = (const float*)d_in[5];
  const float* wik = (const float*)d_in[6];
  const float* cwa = (const float*)d_in[7];
  const float* cwb = (const float*)d_in[8];
  float* out = (float*)d_out;

  float* ws = (float*)d_ws;
  float* qb    = ws;                       // QSZ (q, later attention output)
  float* kb    = qb + QSZ;                 // KSZ
  float* vb    = kb + KSZ;                 // KSZ
  float* cost  = vb + KSZ;                 // T*HALF
  float* sint  = cost + (size_t)TT * HALF; // T*HALF
  float* xpart = sint + (size_t)TT * HALF; // B*16*DIM
  float* ki    = xpart + (size_t)BB * 16 * CDIM;  // B*HD
  float* u     = ki + BB * HD;             // B*DIM
  float* sc    = u + BB * CDIM;            // B*NB
  float* ckb   = sc + BB * NB;             // CSZ
  float* cvb   = ckb + CSZ;                // CSZ
  int* topk    = (int*)(cvb + CSZ);        // B*TOPK

  const int M = BB * TT;

  // projections
  csa_sgemm<<<dim3(CDIM / GBN, M / GBM), 256, 0, stream>>>(x, wq, qb, M, NHQ * HD, CDIM);
  csa_sgemm<<<dim3((NKV * HD) / GBN, M / GBM), 256, 0, stream>>>(x, wk, kb, M, NKV * HD, CDIM);
  csa_sgemm<<<dim3((NKV * HD) / GBN, M / GBM), 256, 0, stream>>>(x, wv, vb, M, NKV * HD, CDIM);

  // RoPE
  csa_rope_table<<<(TT * HALF + 255) / 256, 256, 0, stream>>>(cost, sint);
  int qtot = BB * TT * NHQ * HALF;
  csa_rope_apply<<<(qtot + 255) / 256, 256, 0, stream>>>(qb, cost, sint, NHQ, qtot);
  int ktot = BB * TT * NKV * HALF;
  csa_rope_apply<<<(ktot + 255) / 256, 256, 0, stream>>>(kb, cost, sint, NKV, ktot);

  // selection scores: ki_mean = mean_t(x) @ wik ; scores = x . (wiq @ ki_mean)
  csa_xpart<<<dim3(CDIM / 256, 16, BB), 256, 0, stream>>>(x, xpart);
  csa_kimean<<<BB * HD, 256, 0, stream>>>(xpart, wik, ki);
  csa_u<<<(BB * CDIM) / 256, 256, 0, stream>>>(wiq, ki, u);
  csa_scores<<<BB * NB, 256, 0, stream>>>(x, u, sc);
  csa_topk<<<BB, 256, 0, stream>>>(sc, topk);

  // compress only selected blocks
  csa_compress<<<BB * NKV * TOPK, 64, 0, stream>>>(kb, vb, topk, cwa, cwb, ckb, cvb);

  // attention (overwrites qb with per-head outputs, layout (B,T,H,HD) == (B,T,DIM))
  csa_attn<<<dim3(TT / ATQ, BB * NHQ), 256, 0, stream>>>(qb, ckb, cvb);

  // output projection
  csa_sgemm<<<dim3(CDIM / GBN, M / GBM), 256, 0, stream>>>(qb, wo, out, M, CDIM, CDIM);
}

// Round 2
// 1253.454 us; speedup vs baseline: 2.3966x; 2.3966x over previous
//
#include <hip/hip_runtime.h>
#include <math.h>
#include <stdint.h>

// ---------------- problem constants ----------------
#define BB    2
#define TT    4096
#define CDIM  2048
#define NHQ   16
#define NKV   4
#define HD    128
#define HALF  64
#define NREP  4
#define RBLK  16
#define NB    256
#define TOPK  64

#define MROWS (BB * TT)                    // 8192
#define NQKV  (CDIM + 2 * NKV * HD)        // 3072
#define XELE  ((size_t)MROWS * CDIM)       // 16,777,216
#define CSZ   ((size_t)BB * NKV * TOPK * HD)

typedef __bf16 bf16;
typedef __bf16 bf16x4 __attribute__((ext_vector_type(4)));
typedef __bf16 bf16x8 __attribute__((ext_vector_type(8)));
typedef float f32x4 __attribute__((ext_vector_type(4)));

typedef __attribute__((address_space(1))) unsigned int gu32;
typedef __attribute__((address_space(3))) unsigned int lu32;

__device__ __forceinline__ void gload_lds16(const void* g, void* l) {
  void* gv = const_cast<void*>(g);
  __builtin_amdgcn_global_load_lds((gu32*)gv, (lu32*)l, 16, 0, 0);
}

// ---------------- split-bf16 3-term MFMA GEMM core ----------------
// C[128x128] tile at (bm,bn): A row-major MxK bf16 (hi/lo), B stored as
// B^T row-major NxK bf16 (hi/lo). acc = Ah*Bh + Ah*Bl + Al*Bh.
__device__ __forceinline__ void mfma3_core(const bf16* __restrict__ Ah,
                                           const bf16* __restrict__ Al,
                                           const bf16* __restrict__ Bh,
                                           const bf16* __restrict__ Bl,
                                           int K, int bm, int bn,
                                           f32x4 acc[4][4]) {
  __shared__ bf16 sAh[128 * 32];
  __shared__ bf16 sAl[128 * 32];
  __shared__ bf16 sBh[128 * 32];
  __shared__ bf16 sBl[128 * 32];
  const int tid = threadIdx.x;
  const int wave = tid >> 6, lane = tid & 63;
  const int wrow = (wave & 1) << 6, wcol = (wave >> 1) << 6;
  const int fr = lane & 15, fk = (lane >> 4) << 3;
  const int srow = lane >> 2;          // 0..15
  const int scol = (lane & 3) << 3;    // 0,8,16,24

  const bf16* gsrc;
  bf16* ldst;
  if (wave == 0)      { gsrc = Ah + (size_t)bm * K; ldst = sAh; }
  else if (wave == 1) { gsrc = Al + (size_t)bm * K; ldst = sAl; }
  else if (wave == 2) { gsrc = Bh + (size_t)bn * K; ldst = sBh; }
  else                { gsrc = Bl + (size_t)bn * K; ldst = sBl; }
  gsrc += (size_t)srow * K + scol;

  for (int k0 = 0; k0 < K; k0 += 32) {
    __syncthreads();
#pragma unroll
    for (int c = 0; c < 8; ++c)
      gload_lds16(gsrc + k0 + (size_t)(16 * c) * K, ldst + c * 512);
    __syncthreads();
    bf16x8 fah[4], fal[4], fbh[4], fbl[4];
#pragma unroll
    for (int i = 0; i < 4; ++i) {
      fah[i] = *(const bf16x8*)&sAh[(wrow + i * 16 + fr) * 32 + fk];
      fal[i] = *(const bf16x8*)&sAl[(wrow + i * 16 + fr) * 32 + fk];
      fbh[i] = *(const bf16x8*)&sBh[(wcol + i * 16 + fr) * 32 + fk];
      fbl[i] = *(const bf16x8*)&sBl[(wcol + i * 16 + fr) * 32 + fk];
    }
#pragma unroll
    for (int i = 0; i < 4; ++i)
#pragma unroll
      for (int j = 0; j < 4; ++j) {
        acc[i][j] = __builtin_amdgcn_mfma_f32_16x16x32_bf16(fah[i], fbh[j], acc[i][j], 0, 0, 0);
        acc[i][j] = __builtin_amdgcn_mfma_f32_16x16x32_bf16(fah[i], fbl[j], acc[i][j], 0, 0, 0);
        acc[i][j] = __builtin_amdgcn_mfma_f32_16x16x32_bf16(fal[i], fbh[j], acc[i][j], 0, 0, 0);
      }
  }
}

// fused QKV: N=3072 columns -> q (2048) / k (512) / v (512)
__global__ __launch_bounds__(256) void csa_gemm_qkv(const bf16* __restrict__ xh,
                                                    const bf16* __restrict__ xl,
                                                    const bf16* __restrict__ wth,
                                                    const bf16* __restrict__ wtl,
                                                    float* __restrict__ qb,
                                                    float* __restrict__ kb,
                                                    float* __restrict__ vb) {
  f32x4 acc[4][4] = {};
  const int bm = blockIdx.y << 7, bn = blockIdx.x << 7;
  mfma3_core(xh, xl, wth, wtl, CDIM, bm, bn, acc);
  const int wave = threadIdx.x >> 6, lane = threadIdx.x & 63;
  const int wrow = (wave & 1) << 6, wcol = (wave >> 1) << 6;
  float* dst; int ncols, colofs;
  if (bn < CDIM)            { dst = qb; ncols = CDIM; colofs = bn; }
  else if (bn < CDIM + 512) { dst = kb; ncols = 512;  colofs = bn - CDIM; }
  else                      { dst = vb; ncols = 512;  colofs = bn - CDIM - 512; }
#pragma unroll
  for (int i = 0; i < 4; ++i)
#pragma unroll
    for (int j = 0; j < 4; ++j) {
      int row0 = bm + wrow + i * 16 + ((lane >> 4) << 2);
      int col = colofs + wcol + j * 16 + (lane & 15);
#pragma unroll
      for (int r = 0; r < 4; ++r)
        dst[(size_t)(row0 + r) * ncols + col] = acc[i][j][r];
    }
}

__global__ __launch_bounds__(256) void csa_gemm_wo(const bf16* __restrict__ ah,
                                                   const bf16* __restrict__ al,
                                                   const bf16* __restrict__ wth,
                                                   const bf16* __restrict__ wtl,
                                                   float* __restrict__ C) {
  f32x4 acc[4][4] = {};
  const int bm = blockIdx.y << 7, bn = blockIdx.x << 7;
  mfma3_core(ah, al, wth, wtl, CDIM, bm, bn, acc);
  const int wave = threadIdx.x >> 6, lane = threadIdx.x & 63;
  const int wrow = (wave & 1) << 6, wcol = (wave >> 1) << 6;
#pragma unroll
  for (int i = 0; i < 4; ++i)
#pragma unroll
    for (int j = 0; j < 4; ++j) {
      int row0 = bm + wrow + i * 16 + ((lane >> 4) << 2);
      int col = bn + wcol + j * 16 + (lane & 15);
#pragma unroll
      for (int r = 0; r < 4; ++r)
        C[(size_t)(row0 + r) * CDIM + col] = acc[i][j][r];
    }
}

// ---------------- x -> hi/lo bf16 ----------------
__global__ void csa_xconv(const float4* __restrict__ x, bf16x4* __restrict__ xh,
                          bf16x4* __restrict__ xl) {
  int i = blockIdx.x * 256 + threadIdx.x;  // XELE/4 threads
  float4 v = x[i];
  bf16x4 h, l;
  h[0] = (bf16)v.x; l[0] = (bf16)(v.x - (float)h[0]);
  h[1] = (bf16)v.y; l[1] = (bf16)(v.y - (float)h[1]);
  h[2] = (bf16)v.z; l[2] = (bf16)(v.z - (float)h[2]);
  h[3] = (bf16)v.w; l[3] = (bf16)(v.w - (float)h[3]);
  xh[i] = h;
  xl[i] = l;
}

// ---------------- W (KxN) -> W^T (NxK) hi/lo bf16 ----------------
__global__ __launch_bounds__(256) void csa_wconv(const float* __restrict__ W, int N,
                                                 bf16* __restrict__ wth,
                                                 bf16* __restrict__ wtl, int rowofs) {
  __shared__ float tile[32][33];
  int k0 = blockIdx.y * 32, n0 = blockIdx.x * 32;
  int tx = threadIdx.x & 31, ty = threadIdx.x >> 5;  // 32 x 8
#pragma unroll
  for (int r = 0; r < 32; r += 8)
    tile[ty + r][tx] = W[(size_t)(k0 + ty + r) * N + n0 + tx];
  __syncthreads();
#pragma unroll
  for (int r = 0; r < 32; r += 8) {
    int n = ty + r;
    float x = tile[tx][n];  // = W[k0+tx][n0+n]
    bf16 h = (bf16)x;
    bf16 l = (bf16)(x - (float)h);
    size_t o = (size_t)(rowofs + n0 + n) * CDIM + k0 + tx;
    wth[o] = h;
    wtl[o] = l;
  }
}

// ---------------- RoPE table ----------------
__global__ void csa_rope_table(float* __restrict__ cost, float* __restrict__ sint) {
  int idx = blockIdx.x * blockDim.x + threadIdx.x;
  if (idx >= TT * HALF) return;
  int t = idx / HALF, i = idx % HALF;
  double freq = pow(10000.0, -(double)i / (double)HALF);
  double ang = (double)t * freq;
  cost[idx] = (float)cos(ang);
  sint[idx] = (float)sin(ang);
}

__global__ void csa_rope_apply(float* __restrict__ buf, const float* __restrict__ cost,
                               const float* __restrict__ sint, int nheads, int total) {
  int idx = blockIdx.x * blockDim.x + threadIdx.x;
  if (idx >= total) return;
  int i = idx % HALF;
  int h = (idx / HALF) % nheads;
  int t = (idx / (HALF * nheads)) % TT;
  int b = idx / (HALF * nheads * TT);
  float c = cost[t * HALF + i], s = sint[t * HALF + i];
  float* p = buf + ((((size_t)b * TT + t) * nheads + h) * HD) + 2 * i;
  float a = p[0], q = p[1];
  p[0] = a * c - q * s;
  p[1] = a * s + q * c;
}

// ---------------- selection path ----------------
__global__ void csa_xpart(const float* __restrict__ x, float* __restrict__ xpart) {
  int d = blockIdx.x * 256 + threadIdx.x;
  int ts = blockIdx.y;
  int b = blockIdx.z;
  float s = 0.f;
  int t0 = ts * (TT / 16);
  for (int t = t0; t < t0 + TT / 16; ++t) s += x[((size_t)b * TT + t) * CDIM + d];
  xpart[((size_t)b * 16 + ts) * CDIM + d] = s;
}

__global__ void csa_kimean(const float* __restrict__ xpart, const float* __restrict__ wik,
                           float* __restrict__ ki) {
  int b = blockIdx.x >> 7;
  int j = blockIdx.x & 127;
  int tid = threadIdx.x;
  float s = 0.f;
  for (int d = tid; d < CDIM; d += 256) {
    float xm = 0.f;
#pragma unroll
    for (int ts = 0; ts < 16; ++ts) xm += xpart[((size_t)b * 16 + ts) * CDIM + d];
    s += xm * wik[(size_t)d * HD + j];
  }
  __shared__ float red[256];
  red[tid] = s;
  __syncthreads();
  for (int off = 128; off > 0; off >>= 1) {
    if (tid < off) red[tid] += red[tid + off];
    __syncthreads();
  }
  if (tid == 0) ki[b * HD + j] = red[0] * (1.f / (float)TT);
}

__global__ void csa_u(const float* __restrict__ wiq, const float* __restrict__ ki,
                      float* __restrict__ u) {
  int idx = blockIdx.x * 256 + threadIdx.x;
  int b = idx / CDIM, d = idx % CDIM;
  float s = 0.f;
#pragma unroll 8
  for (int j = 0; j < HD; ++j) s += wiq[(size_t)d * HD + j] * ki[b * HD + j];
  u[idx] = s;
}

__global__ void csa_scores(const float* __restrict__ x, const float* __restrict__ u,
                           float* __restrict__ sc) {
  int b = blockIdx.x >> 8;
  int t = blockIdx.x & 255;
  int tid = threadIdx.x;
  float s = 0.f;
  for (int d = tid; d < CDIM; d += 256)
    s += x[((size_t)b * TT + t) * CDIM + d] * u[b * CDIM + d];
  __shared__ float red[256];
  red[tid] = s;
  __syncthreads();
  for (int off = 128; off > 0; off >>= 1) {
    if (tid < off) red[tid] += red[tid + off];
    __syncthreads();
  }
  if (tid == 0) sc[blockIdx.x] = red[0];
}

__global__ void csa_topk(const float* __restrict__ sc, int* __restrict__ topk) {
  __shared__ float val[NB];
  __shared__ float rv[256];
  __shared__ int ri[256];
  int b = blockIdx.x, tid = threadIdx.x;
  val[tid] = sc[b * NB + tid];
  __syncthreads();
  for (int it = 0; it < TOPK; ++it) {
    rv[tid] = val[tid];
    ri[tid] = tid;
    __syncthreads();
    for (int off = 128; off > 0; off >>= 1) {
      if (tid < off) {
        if (rv[tid + off] > rv[tid] ||
            (rv[tid + off] == rv[tid] && ri[tid + off] < ri[tid])) {
          rv[tid] = rv[tid + off];
          ri[tid] = ri[tid + off];
        }
      }
      __syncthreads();
    }
    if (tid == 0) {
      topk[b * TOPK + it] = ri[0];
      val[ri[0]] = -INFINITY;
    }
    __syncthreads();
  }
}

// ---------------- compress selected blocks ----------------
__global__ __launch_bounds__(64) void csa_compress(const float* __restrict__ kbuf,
                                                   const float* __restrict__ vbuf,
                                                   const int* __restrict__ topk,
                                                   const float* __restrict__ cwa,
                                                   const float* __restrict__ cwb,
                                                   float* __restrict__ ck,
                                                   float* __restrict__ cv) {
  int blk = blockIdx.x;
  int b = blk / (NKV * TOPK);
  int h = (blk / TOPK) % NKV;
  int j = blk % TOPK;
  int n = topk[b * TOPK + j];
  int l = threadIdx.x;
  float ca0 = cwa[l], ca1 = cwa[l + 64];
  float cb0 = cwb[l], cb1 = cwb[l + 64];
  float kk[RBLK][2], vv[RBLK][2], ar[RBLK], br[RBLK];
#pragma unroll
  for (int r = 0; r < RBLK; ++r) {
    int t = n * RBLK + r;
    size_t base = (((size_t)b * TT + t) * NKV + h) * HD;
    kk[r][0] = kbuf[base + l];
    kk[r][1] = kbuf[base + l + 64];
    vv[r][0] = vbuf[base + l];
    vv[r][1] = vbuf[base + l + 64];
    float pa = kk[r][0] * ca0 + kk[r][1] * ca1;
    float pb = kk[r][0] * cb0 + kk[r][1] * cb1;
    for (int off = 32; off > 0; off >>= 1) {
      pa += __shfl_xor(pa, off);
      pb += __shfl_xor(pb, off);
    }
    ar[r] = pa;
    br[r] = pb;
  }
  float ma = -INFINITY, mb = -INFINITY;
#pragma unroll
  for (int r = 0; r < RBLK; ++r) { ma = fmaxf(ma, ar[r]); mb = fmaxf(mb, br[r]); }
  float ea[RBLK], eb[RBLK], sa = 0.f, sb = 0.f;
#pragma unroll
  for (int r = 0; r < RBLK; ++r) {
    ea[r] = expf(ar[r] - ma); sa += ea[r];
    eb[r] = expf(br[r] - mb); sb += eb[r];
  }
  float isa = 1.f / sa, isb = 1.f / sb;
  float o0 = 0.f, o1 = 0.f, p0 = 0.f, p1 = 0.f;
#pragma unroll
  for (int r = 0; r < RBLK; ++r) {
    float w = 0.5f * (ea[r] * isa + eb[r] * isb);
    o0 += w * kk[r][0]; o1 += w * kk[r][1];
    p0 += w * vv[r][0]; p1 += w * vv[r][1];
  }
  size_t cb_ = (((size_t)b * NKV + h) * TOPK + j) * HD;
  ck[cb_ + l] = o0; ck[cb_ + l + 64] = o1;
  cv[cb_ + l] = p0; cv[cb_ + l + 64] = p1;
}

// ---------------- attention; writes bf16 hi/lo output ----------------
#define AQ 64
__global__ __launch_bounds__(256) void csa_attn(const float* __restrict__ qbuf,
                                                const float* __restrict__ ck,
                                                const float* __restrict__ cv,
                                                bf16* __restrict__ oh,
                                                bf16* __restrict__ ol) {
  __shared__ float ckL[TOPK][HD];  // XOR-swizzled: [j][(d&96)|((d^(j&31))&31)]
  __shared__ float cvL[TOPK][HD];
  const int tid = threadIdx.x;
  const int b = blockIdx.y / NKV;
  const int kvh = blockIdx.y % NKV;
  const int tq0 = blockIdx.x * AQ;
  const size_t cbase = ((size_t)(b * NKV + kvh) * TOPK) * HD;
  for (int idx = tid; idx < TOPK * HD; idx += 256) {
    int j = idx >> 7, d = idx & 127;
    int dp = (d & 96) | ((d ^ (j & 31)) & 31);
    ckL[j][dp] = ck[cbase + idx];
    cvL[j][dp] = cv[cbase + idx];
  }
  __syncthreads();
  const int w = tid >> 6, l = tid & 63;
  const int h = kvh * NREP + w;   // this wave's q-head
  const int lsw = l & 31;
  const float scale = 0.08838834764831845f;  // 1/sqrt(128)
  for (int qi = 0; qi < AQ; ++qi) {
    int t = tq0 + qi;
    size_t qbase = (((size_t)b * TT + t) * NHQ + h) * HD;
    float q0 = qbuf[qbase + l];
    float q1 = qbuf[qbase + l + 64];
    float s = 0.f;
#pragma unroll 16
    for (int d = 0; d < 64; ++d)
      s += __shfl(q0, d) * ckL[l][(d & 96) | ((d ^ lsw) & 31)];
#pragma unroll 16
    for (int d = 64; d < 128; ++d)
      s += __shfl(q1, d - 64) * ckL[l][(d & 96) | ((d ^ lsw) & 31)];
    s *= scale;
    float m = s;
    for (int off = 32; off > 0; off >>= 1) m = fmaxf(m, __shfl_xor(m, off));
    float e = expf(s - m);
    float sum = e;
    for (int off = 32; off > 0; off >>= 1) sum += __shfl_xor(sum, off);
    float p = e / sum;
    float o0 = 0.f, o1 = 0.f;
#pragma unroll 16
    for (int j = 0; j < TOPK; ++j) {
      float pj = __shfl(p, j);
      int jsw = j & 31;
      o0 += pj * cvL[j][((l ^ jsw) & 31) | (l & 96)];
      o1 += pj * cvL[j][(((l + 64) ^ jsw) & 31) | ((l + 64) & 96)];
    }
    bf16 h0 = (bf16)o0, h1 = (bf16)o1;
    oh[qbase + l] = h0;       ol[qbase + l] = (bf16)(o0 - (float)h0);
    oh[qbase + l + 64] = h1;  ol[qbase + l + 64] = (bf16)(o1 - (float)h1);
  }
}

// ---------------- launch ----------------
extern "C" void kernel_launch(void* const* d_in, const int* in_sizes, int n_in,
                              void* d_out, int out_size, void* d_ws, size_t ws_size,
                              hipStream_t stream) {
  const float* x   = (const float*)d_in[0];
  const float* wq  = (const float*)d_in[1];
  const float* wk  = (const float*)d_in[2];
  const float* wv  = (const float*)d_in[3];
  const float* wo  = (const float*)d_in[4];
  const float* wiq = (const float*)d_in[5];
  const float* wik = (const float*)d_in[6];
  const float* cwa = (const float*)d_in[7];
  const float* cwb = (const float*)d_in[8];
  float* out = (float*)d_out;

  // q (fp32, M x 2048) lives in d_out until the final GEMM overwrites it.
  float* qb = out;

  float* ws = (float*)d_ws;
  float* kb   = ws;                                  // 4,194,304 f
  float* vb   = kb + (size_t)MROWS * 512;            // 4,194,304 f
  bf16*  xh   = (bf16*)(vb + (size_t)MROWS * 512);   // 16,777,216 bf16
  bf16*  xl   = xh + XELE;
  bf16*  wqh  = xl + XELE;                           // 6,291,456 bf16
  bf16*  wql  = wqh + (size_t)NQKV * CDIM;
  float* cost = (float*)(wql + (size_t)NQKV * CDIM);
  float* sint = cost + (size_t)TT * HALF;
  float* xpart = sint + (size_t)TT * HALF;
  float* ki   = xpart + (size_t)BB * 16 * CDIM;
  float* u    = ki + BB * HD;
  float* sc   = u + BB * CDIM;
  float* ckb  = sc + BB * NB;
  float* cvb  = ckb + CSZ;
  int* topk   = (int*)(cvb + CSZ);
  // aliases (lifetimes disjoint, stream-ordered):
  bf16* oh  = xh;   // attention output hi/lo reuses xh/xl
  bf16* ol_ = xl;
  bf16* woh = wqh;  // wo^T hi/lo reuses wq^T region (converted after QKV GEMM)
  bf16* wol = wql;

  // 1. input conversions
  csa_xconv<<<(XELE / 4) / 256, 256, 0, stream>>>((const float4*)x, (bf16x4*)xh, (bf16x4*)xl);
  csa_wconv<<<dim3(CDIM / 32, CDIM / 32), 256, 0, stream>>>(wq, CDIM, wqh, wql, 0);
  csa_wconv<<<dim3(512 / 32, CDIM / 32), 256, 0, stream>>>(wk, 512, wqh, wql, CDIM);
  csa_wconv<<<dim3(512 / 32, CDIM / 32), 256, 0, stream>>>(wv, 512, wqh, wql, CDIM + 512);

  // 2. fused QKV projection (MFMA, 3-term split)
  csa_gemm_qkv<<<dim3(NQKV / 128, MROWS / 128), 256, 0, stream>>>(xh, xl, wqh, wql, qb, kb, vb);

  // 3. wo transpose+split (reuses wq^T region — must follow QKV GEMM)
  csa_wconv<<<dim3(CDIM / 32, CDIM / 32), 256, 0, stream>>>(wo, CDIM, woh, wol, 0);

  // 4. RoPE
  csa_rope_table<<<(TT * HALF + 255) / 256, 256, 0, stream>>>(cost, sint);
  csa_rope_apply<<<(BB * TT * NHQ * HALF + 255) / 256, 256, 0, stream>>>(qb, cost, sint, NHQ, BB * TT * NHQ * HALF);
  csa_rope_apply<<<(BB * TT * NKV * HALF + 255) / 256, 256, 0, stream>>>(kb, cost, sint, NKV, BB * TT * NKV * HALF);

  // 5. selection: ki_mean = mean_t(x)@wik ; scores = x . (wiq@ki_mean) ; top-64
  csa_xpart<<<dim3(CDIM / 256, 16, BB), 256, 0, stream>>>(x, xpart);
  csa_kimean<<<BB * HD, 256, 0, stream>>>(xpart, wik, ki);
  csa_u<<<(BB * CDIM) / 256, 256, 0, stream>>>(wiq, ki, u);
  csa_scores<<<BB * NB, 256, 0, stream>>>(x, u, sc);
  csa_topk<<<BB, 256, 0, stream>>>(sc, topk);

  // 6. compress only selected blocks
  csa_compress<<<BB * NKV * TOPK, 64, 0, stream>>>(kb, vb, topk, cwa, cwb, ckb, cvb);

  // 7. attention -> bf16 hi/lo output (overwrites xh/xl region)
  csa_attn<<<dim3(TT / AQ, BB * NKV), 256, 0, stream>>>(qb, ckb, cvb, oh, ol_);

  // 8. output projection (MFMA, 3-term split) -> d_out
  csa_gemm_wo<<<dim3(CDIM / 128, MROWS / 128), 256, 0, stream>>>(oh, ol_, woh, wol, out);
}

// Round 3
// 826.880 us; speedup vs baseline: 3.6330x; 1.5159x over previous
//
#include <hip/hip_runtime.h>
#include <math.h>
#include <stdint.h>

// ---------------- problem constants ----------------
#define BB    2
#define TT    4096
#define CDIM  2048
#define NHQ   16
#define NKV   4
#define HD    128
#define HALF  64
#define NREP  4
#define RBLK  16
#define NB    256
#define TOPK  64

#define MROWS (BB * TT)                    // 8192
#define NQKV  (CDIM + 2 * NKV * HD)        // 3072
#define XELE  ((size_t)MROWS * CDIM)       // 16,777,216

typedef __bf16 bf16;
typedef __bf16 bf16x4 __attribute__((ext_vector_type(4)));
typedef __bf16 bf16x8 __attribute__((ext_vector_type(8)));
typedef float f32x4 __attribute__((ext_vector_type(4)));

typedef __attribute__((address_space(1))) unsigned int gu32;
typedef __attribute__((address_space(3))) unsigned int lu32;

__device__ __forceinline__ void gload_lds16(const void* g, void* l) {
  void* gv = const_cast<void*>(g);
  __builtin_amdgcn_global_load_lds((gu32*)gv, (lu32*)l, 16, 0, 0);
}

// ---------------- split-bf16 3-term MFMA GEMM core ----------------
__device__ __forceinline__ void mfma3_core(const bf16* __restrict__ Ah,
                                           const bf16* __restrict__ Al,
                                           const bf16* __restrict__ Bh,
                                           const bf16* __restrict__ Bl,
                                           int K, int bm, int bn,
                                           f32x4 acc[4][4]) {
  __shared__ bf16 sAh[128 * 32];
  __shared__ bf16 sAl[128 * 32];
  __shared__ bf16 sBh[128 * 32];
  __shared__ bf16 sBl[128 * 32];
  const int tid = threadIdx.x;
  const int wave = tid >> 6, lane = tid & 63;
  const int wrow = (wave & 1) << 6, wcol = (wave >> 1) << 6;
  const int fr = lane & 15, fk = (lane >> 4) << 3;
  const int srow = lane >> 2;
  const int scol = (lane & 3) << 3;

  const bf16* gsrc;
  bf16* ldst;
  if (wave == 0)      { gsrc = Ah + (size_t)bm * K; ldst = sAh; }
  else if (wave == 1) { gsrc = Al + (size_t)bm * K; ldst = sAl; }
  else if (wave == 2) { gsrc = Bh + (size_t)bn * K; ldst = sBh; }
  else                { gsrc = Bl + (size_t)bn * K; ldst = sBl; }
  gsrc += (size_t)srow * K + scol;

  for (int k0 = 0; k0 < K; k0 += 32) {
    __syncthreads();
#pragma unroll
    for (int c = 0; c < 8; ++c)
      gload_lds16(gsrc + k0 + (size_t)(16 * c) * K, ldst + c * 512);
    __syncthreads();
    bf16x8 fah[4], fal[4], fbh[4], fbl[4];
#pragma unroll
    for (int i = 0; i < 4; ++i) {
      fah[i] = *(const bf16x8*)&sAh[(wrow + i * 16 + fr) * 32 + fk];
      fal[i] = *(const bf16x8*)&sAl[(wrow + i * 16 + fr) * 32 + fk];
      fbh[i] = *(const bf16x8*)&sBh[(wcol + i * 16 + fr) * 32 + fk];
      fbl[i] = *(const bf16x8*)&sBl[(wcol + i * 16 + fr) * 32 + fk];
    }
#pragma unroll
    for (int i = 0; i < 4; ++i)
#pragma unroll
      for (int j = 0; j < 4; ++j) {
        acc[i][j] = __builtin_amdgcn_mfma_f32_16x16x32_bf16(fah[i], fbh[j], acc[i][j], 0, 0, 0);
        acc[i][j] = __builtin_amdgcn_mfma_f32_16x16x32_bf16(fah[i], fbl[j], acc[i][j], 0, 0, 0);
        acc[i][j] = __builtin_amdgcn_mfma_f32_16x16x32_bf16(fal[i], fbh[j], acc[i][j], 0, 0, 0);
      }
  }
}

__global__ __launch_bounds__(256) void csa_gemm_qkv(const bf16* __restrict__ xh,
                                                    const bf16* __restrict__ xl,
                                                    const bf16* __restrict__ wth,
                                                    const bf16* __restrict__ wtl,
                                                    float* __restrict__ qb,
                                                    float* __restrict__ kb,
                                                    float* __restrict__ vb) {
  f32x4 acc[4][4] = {};
  const int bm = blockIdx.y << 7, bn = blockIdx.x << 7;
  mfma3_core(xh, xl, wth, wtl, CDIM, bm, bn, acc);
  const int wave = threadIdx.x >> 6, lane = threadIdx.x & 63;
  const int wrow = (wave & 1) << 6, wcol = (wave >> 1) << 6;
  float* dst; int ncols, colofs;
  if (bn < CDIM)            { dst = qb; ncols = CDIM; colofs = bn; }
  else if (bn < CDIM + 512) { dst = kb; ncols = 512;  colofs = bn - CDIM; }
  else                      { dst = vb; ncols = 512;  colofs = bn - CDIM - 512; }
#pragma unroll
  for (int i = 0; i < 4; ++i)
#pragma unroll
    for (int j = 0; j < 4; ++j) {
      int row0 = bm + wrow + i * 16 + ((lane >> 4) << 2);
      int col = colofs + wcol + j * 16 + (lane & 15);
#pragma unroll
      for (int r = 0; r < 4; ++r)
        dst[(size_t)(row0 + r) * ncols + col] = acc[i][j][r];
    }
}

__global__ __launch_bounds__(256) void csa_gemm_wo(const bf16* __restrict__ ah,
                                                   const bf16* __restrict__ al,
                                                   const bf16* __restrict__ wth,
                                                   const bf16* __restrict__ wtl,
                                                   float* __restrict__ C) {
  f32x4 acc[4][4] = {};
  const int bm = blockIdx.y << 7, bn = blockIdx.x << 7;
  mfma3_core(ah, al, wth, wtl, CDIM, bm, bn, acc);
  const int wave = threadIdx.x >> 6, lane = threadIdx.x & 63;
  const int wrow = (wave & 1) << 6, wcol = (wave >> 1) << 6;
#pragma unroll
  for (int i = 0; i < 4; ++i)
#pragma unroll
    for (int j = 0; j < 4; ++j) {
      int row0 = bm + wrow + i * 16 + ((lane >> 4) << 2);
      int col = bn + wcol + j * 16 + (lane & 15);
#pragma unroll
      for (int r = 0; r < 4; ++r)
        C[(size_t)(row0 + r) * CDIM + col] = acc[i][j][r];
    }
}

// ---------------- x -> hi/lo bf16 ----------------
__global__ void csa_xconv(const float4* __restrict__ x, bf16x4* __restrict__ xh,
                          bf16x4* __restrict__ xl) {
  int i = blockIdx.x * 256 + threadIdx.x;
  float4 v = x[i];
  bf16x4 h, l;
  h[0] = (bf16)v.x; l[0] = (bf16)(v.x - (float)h[0]);
  h[1] = (bf16)v.y; l[1] = (bf16)(v.y - (float)h[1]);
  h[2] = (bf16)v.z; l[2] = (bf16)(v.z - (float)h[2]);
  h[3] = (bf16)v.w; l[3] = (bf16)(v.w - (float)h[3]);
  xh[i] = h;
  xl[i] = l;
}

// ---------------- W (KxN) -> W^T (NxK) hi/lo bf16 ----------------
__global__ __launch_bounds__(256) void csa_wconv(const float* __restrict__ W, int N,
                                                 bf16* __restrict__ wth,
                                                 bf16* __restrict__ wtl, int rowofs) {
  __shared__ float tile[32][33];
  int k0 = blockIdx.y * 32, n0 = blockIdx.x * 32;
  int tx = threadIdx.x & 31, ty = threadIdx.x >> 5;
#pragma unroll
  for (int r = 0; r < 32; r += 8)
    tile[ty + r][tx] = W[(size_t)(k0 + ty + r) * N + n0 + tx];
  __syncthreads();
#pragma unroll
  for (int r = 0; r < 32; r += 8) {
    int n = ty + r;
    float x = tile[tx][n];
    bf16 h = (bf16)x;
    bf16 l = (bf16)(x - (float)h);
    size_t o = (size_t)(rowofs + n0 + n) * CDIM + k0 + tx;
    wth[o] = h;
    wtl[o] = l;
  }
}

// ---------------- RoPE table ----------------
__global__ void csa_rope_table(float* __restrict__ cost, float* __restrict__ sint) {
  int idx = blockIdx.x * blockDim.x + threadIdx.x;
  if (idx >= TT * HALF) return;
  int t = idx / HALF, i = idx % HALF;
  double freq = pow(10000.0, -(double)i / (double)HALF);
  double ang = (double)t * freq;
  cost[idx] = (float)cos(ang);
  sint[idx] = (float)sin(ang);
}

__global__ void csa_rope_apply(float* __restrict__ buf, const float* __restrict__ cost,
                               const float* __restrict__ sint, int nheads, int total) {
  int idx = blockIdx.x * blockDim.x + threadIdx.x;
  if (idx >= total) return;
  int i = idx % HALF;
  int h = (idx / HALF) % nheads;
  int t = (idx / (HALF * nheads)) % TT;
  int b = idx / (HALF * nheads * TT);
  float c = cost[t * HALF + i], s = sint[t * HALF + i];
  float* p = buf + ((((size_t)b * TT + t) * nheads + h) * HD) + 2 * i;
  float a = p[0], q = p[1];
  p[0] = a * c - q * s;
  p[1] = a * s + q * c;
}

// ---------------- selection path ----------------
__global__ void csa_xpart(const float* __restrict__ x, float* __restrict__ xpart) {
  int d = blockIdx.x * 256 + threadIdx.x;
  int ts = blockIdx.y;
  int b = blockIdx.z;
  float s = 0.f;
  int t0 = ts * (TT / 16);
  for (int t = t0; t < t0 + TT / 16; ++t) s += x[((size_t)b * TT + t) * CDIM + d];
  xpart[((size_t)b * 16 + ts) * CDIM + d] = s;
}

__global__ void csa_kimean(const float* __restrict__ xpart, const float* __restrict__ wik,
                           float* __restrict__ ki) {
  int b = blockIdx.x >> 7;
  int j = blockIdx.x & 127;
  int tid = threadIdx.x;
  float s = 0.f;
  for (int d = tid; d < CDIM; d += 256) {
    float xm = 0.f;
#pragma unroll
    for (int ts = 0; ts < 16; ++ts) xm += xpart[((size_t)b * 16 + ts) * CDIM + d];
    s += xm * wik[(size_t)d * HD + j];
  }
  __shared__ float red[256];
  red[tid] = s;
  __syncthreads();
  for (int off = 128; off > 0; off >>= 1) {
    if (tid < off) red[tid] += red[tid + off];
    __syncthreads();
  }
  if (tid == 0) ki[b * HD + j] = red[0] * (1.f / (float)TT);
}

__global__ void csa_u(const float* __restrict__ wiq, const float* __restrict__ ki,
                      float* __restrict__ u) {
  int idx = blockIdx.x * 256 + threadIdx.x;
  int b = idx / CDIM, d = idx % CDIM;
  float s = 0.f;
#pragma unroll 8
  for (int j = 0; j < HD; ++j) s += wiq[(size_t)d * HD + j] * ki[b * HD + j];
  u[idx] = s;
}

__global__ void csa_scores(const float* __restrict__ x, const float* __restrict__ u,
                           float* __restrict__ sc) {
  int b = blockIdx.x >> 8;
  int t = blockIdx.x & 255;
  int tid = threadIdx.x;
  float s = 0.f;
  for (int d = tid; d < CDIM; d += 256)
    s += x[((size_t)b * TT + t) * CDIM + d] * u[b * CDIM + d];
  __shared__ float red[256];
  red[tid] = s;
  __syncthreads();
  for (int off = 128; off > 0; off >>= 1) {
    if (tid < off) red[tid] += red[tid + off];
    __syncthreads();
  }
  if (tid == 0) sc[blockIdx.x] = red[0];
}

__global__ void csa_topk(const float* __restrict__ sc, int* __restrict__ topk) {
  __shared__ float val[NB];
  __shared__ float rv[256];
  __shared__ int ri[256];
  int b = blockIdx.x, tid = threadIdx.x;
  val[tid] = sc[b * NB + tid];
  __syncthreads();
  for (int it = 0; it < TOPK; ++it) {
    rv[tid] = val[tid];
    ri[tid] = tid;
    __syncthreads();
    for (int off = 128; off > 0; off >>= 1) {
      if (tid < off) {
        if (rv[tid + off] > rv[tid] ||
            (rv[tid + off] == rv[tid] && ri[tid + off] < ri[tid])) {
          rv[tid] = rv[tid + off];
          ri[tid] = ri[tid + off];
        }
      }
      __syncthreads();
    }
    if (tid == 0) {
      topk[b * TOPK + it] = ri[0];
      val[ri[0]] = -INFINITY;
    }
    __syncthreads();
  }
}

// ---------------- compress selected blocks -> split-bf16 MFMA layouts ----------------
// ckh/ckl: [b][kvh][key j (64)][dim d (128)]   (B^T layout for QK^T)
// cvth/cvtl: [b][kvh][dim d (128)][key j (64)] (B^T layout for PV)
__global__ __launch_bounds__(64) void csa_compress(const float* __restrict__ kbuf,
                                                   const float* __restrict__ vbuf,
                                                   const int* __restrict__ topk,
                                                   const float* __restrict__ cwa,
                                                   const float* __restrict__ cwb,
                                                   bf16* __restrict__ ckh,
                                                   bf16* __restrict__ ckl,
                                                   bf16* __restrict__ cvth,
                                                   bf16* __restrict__ cvtl) {
  int blk = blockIdx.x;
  int b = blk / (NKV * TOPK);
  int h = (blk / TOPK) % NKV;
  int j = blk % TOPK;
  int n = topk[b * TOPK + j];
  int l = threadIdx.x;
  float ca0 = cwa[l], ca1 = cwa[l + 64];
  float cb0 = cwb[l], cb1 = cwb[l + 64];
  float kk[RBLK][2], vv[RBLK][2], ar[RBLK], br[RBLK];
#pragma unroll
  for (int r = 0; r < RBLK; ++r) {
    int t = n * RBLK + r;
    size_t base = (((size_t)b * TT + t) * NKV + h) * HD;
    kk[r][0] = kbuf[base + l];
    kk[r][1] = kbuf[base + l + 64];
    vv[r][0] = vbuf[base + l];
    vv[r][1] = vbuf[base + l + 64];
    float pa = kk[r][0] * ca0 + kk[r][1] * ca1;
    float pb = kk[r][0] * cb0 + kk[r][1] * cb1;
    for (int off = 32; off > 0; off >>= 1) {
      pa += __shfl_xor(pa, off);
      pb += __shfl_xor(pb, off);
    }
    ar[r] = pa;
    br[r] = pb;
  }
  float ma = -INFINITY, mb = -INFINITY;
#pragma unroll
  for (int r = 0; r < RBLK; ++r) { ma = fmaxf(ma, ar[r]); mb = fmaxf(mb, br[r]); }
  float ea[RBLK], eb[RBLK], sa = 0.f, sb = 0.f;
#pragma unroll
  for (int r = 0; r < RBLK; ++r) {
    ea[r] = expf(ar[r] - ma); sa += ea[r];
    eb[r] = expf(br[r] - mb); sb += eb[r];
  }
  float isa = 1.f / sa, isb = 1.f / sb;
  float o0 = 0.f, o1 = 0.f, p0 = 0.f, p1 = 0.f;
#pragma unroll
  for (int r = 0; r < RBLK; ++r) {
    float w = 0.5f * (ea[r] * isa + eb[r] * isb);
    o0 += w * kk[r][0]; o1 += w * kk[r][1];
    p0 += w * vv[r][0]; p1 += w * vv[r][1];
  }
  size_t ckbase = ((size_t)(b * NKV + h) * 64 + j) * 128;
  bf16 h0 = (bf16)o0; ckh[ckbase + l] = h0;      ckl[ckbase + l] = (bf16)(o0 - (float)h0);
  bf16 h1 = (bf16)o1; ckh[ckbase + l + 64] = h1; ckl[ckbase + l + 64] = (bf16)(o1 - (float)h1);
  size_t vtbase = (size_t)(b * NKV + h) * (128 * 64);
  bf16 g0 = (bf16)p0; cvth[vtbase + (size_t)l * 64 + j] = g0;
  cvtl[vtbase + (size_t)l * 64 + j] = (bf16)(p0 - (float)g0);
  bf16 g1 = (bf16)p1; cvth[vtbase + (size_t)(l + 64) * 64 + j] = g1;
  cvtl[vtbase + (size_t)(l + 64) * 64 + j] = (bf16)(p1 - (float)g1);
}

// ---------------- MFMA attention: fused q-RoPE, QK^T, softmax, PV ----------------
// Rows: g = t*4 + hrep for fixed (b,kvh); 128 rows/block (32 tokens x 4 heads).
__global__ __launch_bounds__(256) void csa_attn_mfma(const float* __restrict__ qb,
                                                     const float* __restrict__ cost,
                                                     const float* __restrict__ sint,
                                                     const bf16* __restrict__ ckh_g,
                                                     const bf16* __restrict__ ckl_g,
                                                     const bf16* __restrict__ cvth_g,
                                                     const bf16* __restrict__ cvtl_g,
                                                     bf16* __restrict__ oh_g,
                                                     bf16* __restrict__ ol_g) {
  // Phase 1: sck = ck[64 keys][128 dims] (chunk-XOR swizzled).
  // Phase 2: sck reused as P[128 rows][64 keys]; sV = cvT half [64 dims][64 keys].
  __shared__ __align__(16) bf16 sck[2][64 * 128];
  __shared__ __align__(16) bf16 sV[2][64 * 64];
  const int tid = threadIdx.x;
  const int wave = tid >> 6, lane = tid & 63;
  const int b = blockIdx.y >> 2, kvh = blockIdx.y & 3;
  const int row0 = blockIdx.x << 7;
  const int wrow = wave << 5;
  const int lr = lane & 15, lg = lane >> 4;
  const float scale = 0.08838834764831845f;  // 1/sqrt(128)

  const bf16* gkh = ckh_g + (size_t)(b * NKV + kvh) * (64 * 128);
  const bf16* gkl = ckl_g + (size_t)(b * NKV + kvh) * (64 * 128);
  const bf16* gvh = cvth_g + (size_t)(b * NKV + kvh) * (128 * 64);
  const bf16* gvl = cvtl_g + (size_t)(b * NKV + kvh) * (128 * 64);

  // stage ck (16-B chunks, swizzle c' = c ^ (j&15))
  for (int idx = tid; idx < 1024; idx += 256) {
    int j = idx >> 4, c = idx & 15;
    int dst = (j * 16 + (c ^ (j & 15))) * 8;
    *(uint4*)&sck[0][dst] = *(const uint4*)(gkh + j * 128 + c * 8);
    *(uint4*)&sck[1][dst] = *(const uint4*)(gkl + j * 128 + c * 8);
  }
  // stage cvT half 0 (dims 0..63), swizzle c' = c ^ (d&7)
  for (int idx = tid; idx < 512; idx += 256) {
    int d = idx >> 3, c = idx & 7;
    int dst = (d * 8 + (c ^ (d & 7))) * 8;
    *(uint4*)&sV[0][dst] = *(const uint4*)(gvh + d * 64 + c * 8);
    *(uint4*)&sV[1][dst] = *(const uint4*)(gvl + d * 64 + c * 8);
  }

  // load q rows (A-fragments), apply RoPE in-register, split hi/lo
  bf16x8 qfh[2][4], qfl[2][4];
#pragma unroll
  for (int it = 0; it < 2; ++it)
#pragma unroll
    for (int ks = 0; ks < 4; ++ks) {
      int row = wrow + it * 16 + lr;
      int g = row0 + row;
      int t = g >> 2;
      int hh = kvh * NREP + (g & 3);
      int d0 = ks * 32 + (lg << 3);
      const float* qp = qb + (((size_t)b * TT + t) * NHQ + hh) * HD + d0;
      float4 a = *(const float4*)qp;
      float4 b4 = *(const float4*)(qp + 4);
      float4 cs = *(const float4*)&cost[t * HALF + (d0 >> 1)];
      float4 sn = *(const float4*)&sint[t * HALF + (d0 >> 1)];
      float f[8];
      f[0] = a.x * cs.x - a.y * sn.x;  f[1] = a.x * sn.x + a.y * cs.x;
      f[2] = a.z * cs.y - a.w * sn.y;  f[3] = a.z * sn.y + a.w * cs.y;
      f[4] = b4.x * cs.z - b4.y * sn.z; f[5] = b4.x * sn.z + b4.y * cs.z;
      f[6] = b4.z * cs.w - b4.w * sn.w; f[7] = b4.z * sn.w + b4.w * cs.w;
      bf16x8 h8, l8;
#pragma unroll
      for (int u = 0; u < 8; ++u) {
        h8[u] = (bf16)f[u];
        l8[u] = (bf16)(f[u] - (float)h8[u]);
      }
      qfh[it][ks] = h8;
      qfl[it][ks] = l8;
    }
  __syncthreads();

  // QK^T (3-term split)
  f32x4 accS[2][4] = {};
#pragma unroll
  for (int ks = 0; ks < 4; ++ks) {
    bf16x8 kh[4], kl[4];
#pragma unroll
    for (int jt = 0; jt < 4; ++jt) {
      int row = jt * 16 + lr;
      int c = ks * 4 + lg;
      int off = (row * 16 + (c ^ (row & 15))) * 8;
      kh[jt] = *(const bf16x8*)&sck[0][off];
      kl[jt] = *(const bf16x8*)&sck[1][off];
    }
#pragma unroll
    for (int it = 0; it < 2; ++it)
#pragma unroll
      for (int jt = 0; jt < 4; ++jt) {
        accS[it][jt] = __builtin_amdgcn_mfma_f32_16x16x32_bf16(qfh[it][ks], kh[jt], accS[it][jt], 0, 0, 0);
        accS[it][jt] = __builtin_amdgcn_mfma_f32_16x16x32_bf16(qfh[it][ks], kl[jt], accS[it][jt], 0, 0, 0);
        accS[it][jt] = __builtin_amdgcn_mfma_f32_16x16x32_bf16(qfl[it][ks], kh[jt], accS[it][jt], 0, 0, 0);
      }
  }

  // softmax over 64 keys per row (cols live in lanes 0..15 of each quad-group)
#pragma unroll
  for (int it = 0; it < 2; ++it)
#pragma unroll
    for (int r = 0; r < 4; ++r) {
      float v0 = accS[it][0][r] * scale, v1 = accS[it][1][r] * scale;
      float v2 = accS[it][2][r] * scale, v3 = accS[it][3][r] * scale;
      float m = fmaxf(fmaxf(v0, v1), fmaxf(v2, v3));
      for (int off = 8; off > 0; off >>= 1) m = fmaxf(m, __shfl_xor(m, off));
      float e0 = expf(v0 - m), e1 = expf(v1 - m), e2 = expf(v2 - m), e3 = expf(v3 - m);
      float s = e0 + e1 + e2 + e3;
      for (int off = 8; off > 0; off >>= 1) s += __shfl_xor(s, off);
      float inv = 1.f / s;
      accS[it][0][r] = e0 * inv; accS[it][1][r] = e1 * inv;
      accS[it][2][r] = e2 * inv; accS[it][3][r] = e3 * inv;
    }

  __syncthreads();  // all waves done reading sck (ck) before P overwrite

  // write P (split hi/lo) into sck region, [row][key] swizzled
#pragma unroll
  for (int it = 0; it < 2; ++it)
#pragma unroll
    for (int jt = 0; jt < 4; ++jt)
#pragma unroll
      for (int r = 0; r < 4; ++r) {
        int row = wrow + it * 16 + (lg << 2) + r;
        int k = jt * 16 + lr;
        float p = accS[it][jt][r];
        bf16 ph = (bf16)p;
        int c = k >> 3;
        int off = (row * 8 + (c ^ (row & 7))) * 8 + (k & 7);
        sck[0][off] = ph;
        sck[1][off] = (bf16)(p - (float)ph);
      }
  __syncthreads();

  // PV in two 64-dim halves (sV restaged for half 1)
  for (int half = 0; half < 2; ++half) {
    if (half) {
      __syncthreads();
      for (int idx = tid; idx < 512; idx += 256) {
        int d = idx >> 3, c = idx & 7;
        int dst = (d * 8 + (c ^ (d & 7))) * 8;
        *(uint4*)&sV[0][dst] = *(const uint4*)(gvh + (64 + d) * 64 + c * 8);
        *(uint4*)&sV[1][dst] = *(const uint4*)(gvl + (64 + d) * 64 + c * 8);
      }
      __syncthreads();
    }
    f32x4 accO[2][4] = {};
#pragma unroll
    for (int ks = 0; ks < 2; ++ks) {
      bf16x8 pah[2], pal[2], vh[4], vl[4];
#pragma unroll
      for (int it = 0; it < 2; ++it) {
        int row = wrow + it * 16 + lr;
        int c = ks * 4 + lg;
        int off = (row * 8 + (c ^ (row & 7))) * 8;
        pah[it] = *(const bf16x8*)&sck[0][off];
        pal[it] = *(const bf16x8*)&sck[1][off];
      }
#pragma unroll
      for (int jt = 0; jt < 4; ++jt) {
        int d = jt * 16 + lr;
        int c = ks * 4 + lg;
        int off = (d * 8 + (c ^ (d & 7))) * 8;
        vh[jt] = *(const bf16x8*)&sV[0][off];
        vl[jt] = *(const bf16x8*)&sV[1][off];
      }
#pragma unroll
      for (int it = 0; it < 2; ++it)
#pragma unroll
        for (int jt = 0; jt < 4; ++jt) {
          accO[it][jt] = __builtin_amdgcn_mfma_f32_16x16x32_bf16(pah[it], vh[jt], accO[it][jt], 0, 0, 0);
          accO[it][jt] = __builtin_amdgcn_mfma_f32_16x16x32_bf16(pah[it], vl[jt], accO[it][jt], 0, 0, 0);
          accO[it][jt] = __builtin_amdgcn_mfma_f32_16x16x32_bf16(pal[it], vh[jt], accO[it][jt], 0, 0, 0);
        }
    }
    // epilogue: write o (split hi/lo) to (b,t,h,d)
#pragma unroll
    for (int it = 0; it < 2; ++it)
#pragma unroll
      for (int jt = 0; jt < 4; ++jt)
#pragma unroll
        for (int r = 0; r < 4; ++r) {
          int row = wrow + it * 16 + (lg << 2) + r;
          int g = row0 + row;
          int t = g >> 2;
          int hh = kvh * NREP + (g & 3);
          size_t ob = (((size_t)b * TT + t) * NHQ + hh) * HD + half * 64 + jt * 16 + lr;
          float o = accO[it][jt][r];
          bf16 oh = (bf16)o;
          oh_g[ob] = oh;
          ol_g[ob] = (bf16)(o - (float)oh);
        }
  }
}

// ---------------- launch ----------------
extern "C" void kernel_launch(void* const* d_in, const int* in_sizes, int n_in,
                              void* d_out, int out_size, void* d_ws, size_t ws_size,
                              hipStream_t stream) {
  const float* x   = (const float*)d_in[0];
  const float* wq  = (const float*)d_in[1];
  const float* wk  = (const float*)d_in[2];
  const float* wv  = (const float*)d_in[3];
  const float* wo  = (const float*)d_in[4];
  const float* wiq = (const float*)d_in[5];
  const float* wik = (const float*)d_in[6];
  const float* cwa = (const float*)d_in[7];
  const float* cwb = (const float*)d_in[8];
  float* out = (float*)d_out;

  float* qb = out;  // q fp32 lives in d_out until the final GEMM overwrites it

  float* ws = (float*)d_ws;
  float* kb   = ws;
  float* vb   = kb + (size_t)MROWS * 512;
  bf16*  xh   = (bf16*)(vb + (size_t)MROWS * 512);
  bf16*  xl   = xh + XELE;
  bf16*  wqh  = xl + XELE;
  bf16*  wql  = wqh + (size_t)NQKV * CDIM;
  float* cost = (float*)(wql + (size_t)NQKV * CDIM);
  float* sint = cost + (size_t)TT * HALF;
  float* xpart = sint + (size_t)TT * HALF;
  float* ki   = xpart + (size_t)BB * 16 * CDIM;
  float* u    = ki + BB * HD;
  float* sc   = u + BB * CDIM;
  bf16*  ckh  = (bf16*)(sc + BB * NB);
  bf16*  ckl  = ckh + (size_t)BB * NKV * 64 * 128;
  bf16*  cvth = ckl + (size_t)BB * NKV * 64 * 128;
  bf16*  cvtl = cvth + (size_t)BB * NKV * 128 * 64;
  int* topk   = (int*)(cvtl + (size_t)BB * NKV * 128 * 64);
  // aliases (disjoint lifetimes, stream-ordered):
  bf16* oh  = xh;   // attention output hi/lo reuses xh/xl
  bf16* ol_ = xl;
  bf16* woh = wqh;  // wo^T hi/lo reuses wq^T region (converted after QKV GEMM)
  bf16* wol = wql;

  // 1. input conversions
  csa_xconv<<<(XELE / 4) / 256, 256, 0, stream>>>((const float4*)x, (bf16x4*)xh, (bf16x4*)xl);
  csa_wconv<<<dim3(CDIM / 32, CDIM / 32), 256, 0, stream>>>(wq, CDIM, wqh, wql, 0);
  csa_wconv<<<dim3(512 / 32, CDIM / 32), 256, 0, stream>>>(wk, 512, wqh, wql, CDIM);
  csa_wconv<<<dim3(512 / 32, CDIM / 32), 256, 0, stream>>>(wv, 512, wqh, wql, CDIM + 512);

  // 2. fused QKV projection
  csa_gemm_qkv<<<dim3(NQKV / 128, MROWS / 128), 256, 0, stream>>>(xh, xl, wqh, wql, qb, kb, vb);

  // 3. wo transpose+split (reuses wq^T region)
  csa_wconv<<<dim3(CDIM / 32, CDIM / 32), 256, 0, stream>>>(wo, CDIM, woh, wol, 0);

  // 4. RoPE table + apply to k only (q RoPE fused into attention)
  csa_rope_table<<<(TT * HALF + 255) / 256, 256, 0, stream>>>(cost, sint);
  csa_rope_apply<<<(BB * TT * NKV * HALF + 255) / 256, 256, 0, stream>>>(kb, cost, sint, NKV, BB * TT * NKV * HALF);

  // 5. selection
  csa_xpart<<<dim3(CDIM / 256, 16, BB), 256, 0, stream>>>(x, xpart);
  csa_kimean<<<BB * HD, 256, 0, stream>>>(xpart, wik, ki);
  csa_u<<<(BB * CDIM) / 256, 256, 0, stream>>>(wiq, ki, u);
  csa_scores<<<BB * NB, 256, 0, stream>>>(x, u, sc);
  csa_topk<<<BB, 256, 0, stream>>>(sc, topk);

  // 6. compress selected blocks -> split-bf16 MFMA layouts
  csa_compress<<<BB * NKV * TOPK, 64, 0, stream>>>(kb, vb, topk, cwa, cwb, ckh, ckl, cvth, cvtl);

  // 7. MFMA attention (fused q-RoPE) -> split-bf16 output
  csa_attn_mfma<<<dim3((TT * NREP) / 128, BB * NKV), 256, 0, stream>>>(qb, cost, sint, ckh, ckl, cvth, cvtl, oh, ol_);

  // 8. output projection -> d_out
  csa_gemm_wo<<<dim3(CDIM / 128, MROWS / 128), 256, 0, stream>>>(oh, ol_, woh, wol, out);
}

// Round 4
// 783.847 us; speedup vs baseline: 3.8324x; 1.0549x over previous
//
#include <hip/hip_runtime.h>
#include <math.h>
#include <stdint.h>

// ---------------- problem constants ----------------
#define BB    2
#define TT    4096
#define CDIM  2048
#define NHQ   16
#define NKV   4
#define HD    128
#define HALF  64
#define NREP  4
#define RBLK  16
#define NB    256
#define TOPK  64

#define MROWS (BB * TT)                    // 8192
#define NQKV  (CDIM + 2 * NKV * HD)        // 3072
#define XELE  ((size_t)MROWS * CDIM)       // 16,777,216

typedef __bf16 bf16;
typedef __bf16 bf16x4 __attribute__((ext_vector_type(4)));
typedef __bf16 bf16x8 __attribute__((ext_vector_type(8)));
typedef float f32x4 __attribute__((ext_vector_type(4)));

typedef __attribute__((address_space(1))) unsigned int gu32;
typedef __attribute__((address_space(3))) unsigned int lu32;

__device__ __forceinline__ void gload_lds16(const void* g, void* l) {
  void* gv = const_cast<void*>(g);
  __builtin_amdgcn_global_load_lds((gu32*)gv, (lu32*)l, 16, 0, 0);
}

// ---------------- split-bf16 3-term MFMA GEMM core ----------------
// Block tile 256x128, 4 waves, each wave computes 128x64 (acc[8][4]).
// A row-major MxK bf16 (hi/lo), B stored as B^T row-major NxK bf16 (hi/lo).
// acc = Ah*Bh + Ah*Bl + Al*Bh.
// LDS staged via global_load_lds w/ source-chunk XOR swizzle so fragment
// ds_read_b128 hits only 2-way bank aliasing (free on gfx950).
__device__ __forceinline__ void mfma3_core(const bf16* __restrict__ Ah,
                                           const bf16* __restrict__ Al,
                                           const bf16* __restrict__ Bh,
                                           const bf16* __restrict__ Bl,
                                           int K, int bm, int bn,
                                           f32x4 acc[8][4]) {
  __shared__ bf16 sAh[256 * 32];
  __shared__ bf16 sAl[256 * 32];
  __shared__ bf16 sBh[128 * 32];
  __shared__ bf16 sBl[128 * 32];
  const int tid = threadIdx.x;
  const int wave = tid >> 6, lane = tid & 63;
  const int wr = wave >> 1, wc = wave & 1;
  const int fr = lane & 15, lg = lane >> 4;
  const int lr4 = lane >> 2;
  // staging: LDS slot chunk cs = lane&3 receives global chunk cs ^ ((row>>1)&3);
  // row = 16*call + (lane>>2), so (row>>1)&3 = (lane>>3)&3 for every call.
  const int cgs = (lane & 3) ^ ((lane >> 3) & 3);
  const size_t stageoff = (size_t)lr4 * K + cgs * 8;

  const bf16* gAh = Ah + (size_t)bm * K + stageoff;
  const bf16* gAl = Al + (size_t)bm * K + stageoff;
  const bf16* gBh = Bh + (size_t)bn * K + stageoff;
  const bf16* gBl = Bl + (size_t)bn * K + stageoff;

  // fragment read: row r, chunk lg stored at chunk lg ^ ((r>>1)&3) = lg ^ ((fr>>1)&3)
  const int swf = (fr >> 1) & 3;
  const int aoffe = (wr * 128 + fr) * 32 + ((lg ^ swf) << 3);
  const int boffe = (wc * 64 + fr) * 32 + ((lg ^ swf) << 3);

  for (int k0 = 0; k0 < K; k0 += 32) {
    __syncthreads();
    // 48 wave-calls of 1 KiB each, split 12 per wave
    if (wave == 0) {
#pragma unroll
      for (int u = 0; u < 12; ++u)
        gload_lds16(gAh + (size_t)(u * 16) * K + k0, sAh + u * 512);
    } else if (wave == 1) {
#pragma unroll
      for (int u = 12; u < 16; ++u)
        gload_lds16(gAh + (size_t)(u * 16) * K + k0, sAh + u * 512);
#pragma unroll
      for (int u = 0; u < 8; ++u)
        gload_lds16(gAl + (size_t)(u * 16) * K + k0, sAl + u * 512);
    } else if (wave == 2) {
#pragma unroll
      for (int u = 8; u < 16; ++u)
        gload_lds16(gAl + (size_t)(u * 16) * K + k0, sAl + u * 512);
#pragma unroll
      for (int u = 0; u < 4; ++u)
        gload_lds16(gBh + (size_t)(u * 16) * K + k0, sBh + u * 512);
    } else {
#pragma unroll
      for (int u = 4; u < 8; ++u)
        gload_lds16(gBh + (size_t)(u * 16) * K + k0, sBh + u * 512);
#pragma unroll
      for (int u = 0; u < 8; ++u)
        gload_lds16(gBl + (size_t)(u * 16) * K + k0, sBl + u * 512);
    }
    __syncthreads();
    bf16x8 fah[8], fal[8];
#pragma unroll
    for (int i = 0; i < 8; ++i) {
      fah[i] = *(const bf16x8*)&sAh[aoffe + i * 512];
      fal[i] = *(const bf16x8*)&sAl[aoffe + i * 512];
    }
#pragma unroll
    for (int j = 0; j < 4; ++j) {
      bf16x8 fbh = *(const bf16x8*)&sBh[boffe + j * 512];
      bf16x8 fbl = *(const bf16x8*)&sBl[boffe + j * 512];
#pragma unroll
      for (int i = 0; i < 8; ++i) {
        acc[i][j] = __builtin_amdgcn_mfma_f32_16x16x32_bf16(fah[i], fbh, acc[i][j], 0, 0, 0);
        acc[i][j] = __builtin_amdgcn_mfma_f32_16x16x32_bf16(fah[i], fbl, acc[i][j], 0, 0, 0);
        acc[i][j] = __builtin_amdgcn_mfma_f32_16x16x32_bf16(fal[i], fbh, acc[i][j], 0, 0, 0);
      }
    }
  }
}

__global__ __launch_bounds__(256, 2) void csa_gemm_qkv(const bf16* __restrict__ xh,
                                                       const bf16* __restrict__ xl,
                                                       const bf16* __restrict__ wth,
                                                       const bf16* __restrict__ wtl,
                                                       float* __restrict__ qb,
                                                       float* __restrict__ kb,
                                                       float* __restrict__ vb) {
  f32x4 acc[8][4] = {};
  const int bm = blockIdx.y << 8, bn = blockIdx.x << 7;
  mfma3_core(xh, xl, wth, wtl, CDIM, bm, bn, acc);
  const int wave = threadIdx.x >> 6, lane = threadIdx.x & 63;
  const int wr = wave >> 1, wc = wave & 1;
  const int fr = lane & 15, lg = lane >> 4;
  float* dst; int ncols, colofs;
  if (bn < CDIM)            { dst = qb; ncols = CDIM; colofs = bn; }
  else if (bn < CDIM + 512) { dst = kb; ncols = 512;  colofs = bn - CDIM; }
  else                      { dst = vb; ncols = 512;  colofs = bn - CDIM - 512; }
#pragma unroll
  for (int i = 0; i < 8; ++i)
#pragma unroll
    for (int j = 0; j < 4; ++j) {
      int row0 = bm + wr * 128 + i * 16 + (lg << 2);
      int col = colofs + wc * 64 + j * 16 + fr;
#pragma unroll
      for (int r = 0; r < 4; ++r)
        dst[(size_t)(row0 + r) * ncols + col] = acc[i][j][r];
    }
}

__global__ __launch_bounds__(256, 2) void csa_gemm_wo(const bf16* __restrict__ ah,
                                                      const bf16* __restrict__ al,
                                                      const bf16* __restrict__ wth,
                                                      const bf16* __restrict__ wtl,
                                                      float* __restrict__ C) {
  f32x4 acc[8][4] = {};
  const int bm = blockIdx.y << 8, bn = blockIdx.x << 7;
  mfma3_core(ah, al, wth, wtl, CDIM, bm, bn, acc);
  const int wave = threadIdx.x >> 6, lane = threadIdx.x & 63;
  const int wr = wave >> 1, wc = wave & 1;
  const int fr = lane & 15, lg = lane >> 4;
#pragma unroll
  for (int i = 0; i < 8; ++i)
#pragma unroll
    for (int j = 0; j < 4; ++j) {
      int row0 = bm + wr * 128 + i * 16 + (lg << 2);
      int col = bn + wc * 64 + j * 16 + fr;
#pragma unroll
      for (int r = 0; r < 4; ++r)
        C[(size_t)(row0 + r) * CDIM + col] = acc[i][j][r];
    }
}

// ---------------- x -> hi/lo bf16 ----------------
__global__ void csa_xconv(const float4* __restrict__ x, bf16x4* __restrict__ xh,
                          bf16x4* __restrict__ xl) {
  int i = blockIdx.x * 256 + threadIdx.x;
  float4 v = x[i];
  bf16x4 h, l;
  h[0] = (bf16)v.x; l[0] = (bf16)(v.x - (float)h[0]);
  h[1] = (bf16)v.y; l[1] = (bf16)(v.y - (float)h[1]);
  h[2] = (bf16)v.z; l[2] = (bf16)(v.z - (float)h[2]);
  h[3] = (bf16)v.w; l[3] = (bf16)(v.w - (float)h[3]);
  xh[i] = h;
  xl[i] = l;
}

// ---------------- W (KxN) -> W^T (NxK) hi/lo bf16 ----------------
__global__ __launch_bounds__(256) void csa_wconv(const float* __restrict__ W, int N,
                                                 bf16* __restrict__ wth,
                                                 bf16* __restrict__ wtl, int rowofs) {
  __shared__ float tile[32][33];
  int k0 = blockIdx.y * 32, n0 = blockIdx.x * 32;
  int tx = threadIdx.x & 31, ty = threadIdx.x >> 5;
#pragma unroll
  for (int r = 0; r < 32; r += 8)
    tile[ty + r][tx] = W[(size_t)(k0 + ty + r) * N + n0 + tx];
  __syncthreads();
#pragma unroll
  for (int r = 0; r < 32; r += 8) {
    int n = ty + r;
    float x = tile[tx][n];
    bf16 h = (bf16)x;
    bf16 l = (bf16)(x - (float)h);
    size_t o = (size_t)(rowofs + n0 + n) * CDIM + k0 + tx;
    wth[o] = h;
    wtl[o] = l;
  }
}

// ---------------- RoPE table ----------------
__global__ void csa_rope_table(float* __restrict__ cost, float* __restrict__ sint) {
  int idx = blockIdx.x * blockDim.x + threadIdx.x;
  if (idx >= TT * HALF) return;
  int t = idx / HALF, i = idx % HALF;
  double freq = pow(10000.0, -(double)i / (double)HALF);
  double ang = (double)t * freq;
  cost[idx] = (float)cos(ang);
  sint[idx] = (float)sin(ang);
}

__global__ void csa_rope_apply(float* __restrict__ buf, const float* __restrict__ cost,
                               const float* __restrict__ sint, int nheads, int total) {
  int idx = blockIdx.x * blockDim.x + threadIdx.x;
  if (idx >= total) return;
  int i = idx % HALF;
  int h = (idx / HALF) % nheads;
  int t = (idx / (HALF * nheads)) % TT;
  int b = idx / (HALF * nheads * TT);
  float c = cost[t * HALF + i], s = sint[t * HALF + i];
  float* p = buf + ((((size_t)b * TT + t) * nheads + h) * HD) + 2 * i;
  float a = p[0], q = p[1];
  p[0] = a * c - q * s;
  p[1] = a * s + q * c;
}

// ---------------- selection path ----------------
__global__ void csa_xpart(const float* __restrict__ x, float* __restrict__ xpart) {
  int d = blockIdx.x * 256 + threadIdx.x;
  int ts = blockIdx.y;
  int b = blockIdx.z;
  float s = 0.f;
  int t0 = ts * (TT / 16);
  for (int t = t0; t < t0 + TT / 16; ++t) s += x[((size_t)b * TT + t) * CDIM + d];
  xpart[((size_t)b * 16 + ts) * CDIM + d] = s;
}

__global__ void csa_kimean(const float* __restrict__ xpart, const float* __restrict__ wik,
                           float* __restrict__ ki) {
  int b = blockIdx.x >> 7;
  int j = blockIdx.x & 127;
  int tid = threadIdx.x;
  float s = 0.f;
  for (int d = tid; d < CDIM; d += 256) {
    float xm = 0.f;
#pragma unroll
    for (int ts = 0; ts < 16; ++ts) xm += xpart[((size_t)b * 16 + ts) * CDIM + d];
    s += xm * wik[(size_t)d * HD + j];
  }
  __shared__ float red[256];
  red[tid] = s;
  __syncthreads();
  for (int off = 128; off > 0; off >>= 1) {
    if (tid < off) red[tid] += red[tid + off];
    __syncthreads();
  }
  if (tid == 0) ki[b * HD + j] = red[0] * (1.f / (float)TT);
}

__global__ void csa_u(const float* __restrict__ wiq, const float* __restrict__ ki,
                      float* __restrict__ u) {
  int idx = blockIdx.x * 256 + threadIdx.x;
  int b = idx / CDIM, d = idx % CDIM;
  float s = 0.f;
#pragma unroll 8
  for (int j = 0; j < HD; ++j) s += wiq[(size_t)d * HD + j] * ki[b * HD + j];
  u[idx] = s;
}

__global__ void csa_scores(const float* __restrict__ x, const float* __restrict__ u,
                           float* __restrict__ sc) {
  int b = blockIdx.x >> 8;
  int t = blockIdx.x & 255;
  int tid = threadIdx.x;
  float s = 0.f;
  for (int d = tid; d < CDIM; d += 256)
    s += x[((size_t)b * TT + t) * CDIM + d] * u[b * CDIM + d];
  __shared__ float red[256];
  red[tid] = s;
  __syncthreads();
  for (int off = 128; off > 0; off >>= 1) {
    if (tid < off) red[tid] += red[tid + off];
    __syncthreads();
  }
  if (tid == 0) sc[blockIdx.x] = red[0];
}

__global__ void csa_topk(const float* __restrict__ sc, int* __restrict__ topk) {
  __shared__ float val[NB];
  __shared__ float rv[256];
  __shared__ int ri[256];
  int b = blockIdx.x, tid = threadIdx.x;
  val[tid] = sc[b * NB + tid];
  __syncthreads();
  for (int it = 0; it < TOPK; ++it) {
    rv[tid] = val[tid];
    ri[tid] = tid;
    __syncthreads();
    for (int off = 128; off > 0; off >>= 1) {
      if (tid < off) {
        if (rv[tid + off] > rv[tid] ||
            (rv[tid + off] == rv[tid] && ri[tid + off] < ri[tid])) {
          rv[tid] = rv[tid + off];
          ri[tid] = ri[tid + off];
        }
      }
      __syncthreads();
    }
    if (tid == 0) {
      topk[b * TOPK + it] = ri[0];
      val[ri[0]] = -INFINITY;
    }
    __syncthreads();
  }
}

// ---------------- compress selected blocks -> split-bf16 MFMA layouts ----------------
// ckh/ckl: [b][kvh][key j (64)][dim d (128)]   (B^T layout for QK^T)
// cvth/cvtl: [b][kvh][dim d (128)][key j (64)] (B^T layout for PV)
__global__ __launch_bounds__(64) void csa_compress(const float* __restrict__ kbuf,
                                                   const float* __restrict__ vbuf,
                                                   const int* __restrict__ topk,
                                                   const float* __restrict__ cwa,
                                                   const float* __restrict__ cwb,
                                                   bf16* __restrict__ ckh,
                                                   bf16* __restrict__ ckl,
                                                   bf16* __restrict__ cvth,
                                                   bf16* __restrict__ cvtl) {
  int blk = blockIdx.x;
  int b = blk / (NKV * TOPK);
  int h = (blk / TOPK) % NKV;
  int j = blk % TOPK;
  int n = topk[b * TOPK + j];
  int l = threadIdx.x;
  float ca0 = cwa[l], ca1 = cwa[l + 64];
  float cb0 = cwb[l], cb1 = cwb[l + 64];
  float kk[RBLK][2], vv[RBLK][2], ar[RBLK], br[RBLK];
#pragma unroll
  for (int r = 0; r < RBLK; ++r) {
    int t = n * RBLK + r;
    size_t base = (((size_t)b * TT + t) * NKV + h) * HD;
    kk[r][0] = kbuf[base + l];
    kk[r][1] = kbuf[base + l + 64];
    vv[r][0] = vbuf[base + l];
    vv[r][1] = vbuf[base + l + 64];
    float pa = kk[r][0] * ca0 + kk[r][1] * ca1;
    float pb = kk[r][0] * cb0 + kk[r][1] * cb1;
    for (int off = 32; off > 0; off >>= 1) {
      pa += __shfl_xor(pa, off);
      pb += __shfl_xor(pb, off);
    }
    ar[r] = pa;
    br[r] = pb;
  }
  float ma = -INFINITY, mb = -INFINITY;
#pragma unroll
  for (int r = 0; r < RBLK; ++r) { ma = fmaxf(ma, ar[r]); mb = fmaxf(mb, br[r]); }
  float ea[RBLK], eb[RBLK], sa = 0.f, sb = 0.f;
#pragma unroll
  for (int r = 0; r < RBLK; ++r) {
    ea[r] = expf(ar[r] - ma); sa += ea[r];
    eb[r] = expf(br[r] - mb); sb += eb[r];
  }
  float isa = 1.f / sa, isb = 1.f / sb;
  float o0 = 0.f, o1 = 0.f, p0 = 0.f, p1 = 0.f;
#pragma unroll
  for (int r = 0; r < RBLK; ++r) {
    float w = 0.5f * (ea[r] * isa + eb[r] * isb);
    o0 += w * kk[r][0]; o1 += w * kk[r][1];
    p0 += w * vv[r][0]; p1 += w * vv[r][1];
  }
  size_t ckbase = ((size_t)(b * NKV + h) * 64 + j) * 128;
  bf16 h0 = (bf16)o0; ckh[ckbase + l] = h0;      ckl[ckbase + l] = (bf16)(o0 - (float)h0);
  bf16 h1 = (bf16)o1; ckh[ckbase + l + 64] = h1; ckl[ckbase + l + 64] = (bf16)(o1 - (float)h1);
  size_t vtbase = (size_t)(b * NKV + h) * (128 * 64);
  bf16 g0 = (bf16)p0; cvth[vtbase + (size_t)l * 64 + j] = g0;
  cvtl[vtbase + (size_t)l * 64 + j] = (bf16)(p0 - (float)g0);
  bf16 g1 = (bf16)p1; cvth[vtbase + (size_t)(l + 64) * 64 + j] = g1;
  cvtl[vtbase + (size_t)(l + 64) * 64 + j] = (bf16)(p1 - (float)g1);
}

// ---------------- MFMA attention: fused q-RoPE, QK^T, softmax, PV ----------------
// Rows: g = t*4 + hrep for fixed (b,kvh); 128 rows/block (32 tokens x 4 heads).
__global__ __launch_bounds__(256) void csa_attn_mfma(const float* __restrict__ qb,
                                                     const float* __restrict__ cost,
                                                     const float* __restrict__ sint,
                                                     const bf16* __restrict__ ckh_g,
                                                     const bf16* __restrict__ ckl_g,
                                                     const bf16* __restrict__ cvth_g,
                                                     const bf16* __restrict__ cvtl_g,
                                                     bf16* __restrict__ oh_g,
                                                     bf16* __restrict__ ol_g) {
  __shared__ __align__(16) bf16 sck[2][64 * 128];
  __shared__ __align__(16) bf16 sV[2][64 * 64];
  const int tid = threadIdx.x;
  const int wave = tid >> 6, lane = tid & 63;
  const int b = blockIdx.y >> 2, kvh = blockIdx.y & 3;
  const int row0 = blockIdx.x << 7;
  const int wrow = wave << 5;
  const int lr = lane & 15, lg = lane >> 4;
  const float scale = 0.08838834764831845f;  // 1/sqrt(128)

  const bf16* gkh = ckh_g + (size_t)(b * NKV + kvh) * (64 * 128);
  const bf16* gkl = ckl_g + (size_t)(b * NKV + kvh) * (64 * 128);
  const bf16* gvh = cvth_g + (size_t)(b * NKV + kvh) * (128 * 64);
  const bf16* gvl = cvtl_g + (size_t)(b * NKV + kvh) * (128 * 64);

  for (int idx = tid; idx < 1024; idx += 256) {
    int j = idx >> 4, c = idx & 15;
    int dst = (j * 16 + (c ^ (j & 15))) * 8;
    *(uint4*)&sck[0][dst] = *(const uint4*)(gkh + j * 128 + c * 8);
    *(uint4*)&sck[1][dst] = *(const uint4*)(gkl + j * 128 + c * 8);
  }
  for (int idx = tid; idx < 512; idx += 256) {
    int d = idx >> 3, c = idx & 7;
    int dst = (d * 8 + (c ^ (d & 7))) * 8;
    *(uint4*)&sV[0][dst] = *(const uint4*)(gvh + d * 64 + c * 8);
    *(uint4*)&sV[1][dst] = *(const uint4*)(gvl + d * 64 + c * 8);
  }

  bf16x8 qfh[2][4], qfl[2][4];
#pragma unroll
  for (int it = 0; it < 2; ++it)
#pragma unroll
    for (int ks = 0; ks < 4; ++ks) {
      int row = wrow + it * 16 + lr;
      int g = row0 + row;
      int t = g >> 2;
      int hh = kvh * NREP + (g & 3);
      int d0 = ks * 32 + (lg << 3);
      const float* qp = qb + (((size_t)b * TT + t) * NHQ + hh) * HD + d0;
      float4 a = *(const float4*)qp;
      float4 b4 = *(const float4*)(qp + 4);
      float4 cs = *(const float4*)&cost[t * HALF + (d0 >> 1)];
      float4 sn = *(const float4*)&sint[t * HALF + (d0 >> 1)];
      float f[8];
      f[0] = a.x * cs.x - a.y * sn.x;  f[1] = a.x * sn.x + a.y * cs.x;
      f[2] = a.z * cs.y - a.w * sn.y;  f[3] = a.z * sn.y + a.w * cs.y;
      f[4] = b4.x * cs.z - b4.y * sn.z; f[5] = b4.x * sn.z + b4.y * cs.z;
      f[6] = b4.z * cs.w - b4.w * sn.w; f[7] = b4.z * sn.w + b4.w * cs.w;
      bf16x8 h8, l8;
#pragma unroll
      for (int u = 0; u < 8; ++u) {
        h8[u] = (bf16)f[u];
        l8[u] = (bf16)(f[u] - (float)h8[u]);
      }
      qfh[it][ks] = h8;
      qfl[it][ks] = l8;
    }
  __syncthreads();

  f32x4 accS[2][4] = {};
#pragma unroll
  for (int ks = 0; ks < 4; ++ks) {
    bf16x8 kh[4], kl[4];
#pragma unroll
    for (int jt = 0; jt < 4; ++jt) {
      int row = jt * 16 + lr;
      int c = ks * 4 + lg;
      int off = (row * 16 + (c ^ (row & 15))) * 8;
      kh[jt] = *(const bf16x8*)&sck[0][off];
      kl[jt] = *(const bf16x8*)&sck[1][off];
    }
#pragma unroll
    for (int it = 0; it < 2; ++it)
#pragma unroll
      for (int jt = 0; jt < 4; ++jt) {
        accS[it][jt] = __builtin_amdgcn_mfma_f32_16x16x32_bf16(qfh[it][ks], kh[jt], accS[it][jt], 0, 0, 0);
        accS[it][jt] = __builtin_amdgcn_mfma_f32_16x16x32_bf16(qfh[it][ks], kl[jt], accS[it][jt], 0, 0, 0);
        accS[it][jt] = __builtin_amdgcn_mfma_f32_16x16x32_bf16(qfl[it][ks], kh[jt], accS[it][jt], 0, 0, 0);
      }
  }

#pragma unroll
  for (int it = 0; it < 2; ++it)
#pragma unroll
    for (int r = 0; r < 4; ++r) {
      float v0 = accS[it][0][r] * scale, v1 = accS[it][1][r] * scale;
      float v2 = accS[it][2][r] * scale, v3 = accS[it][3][r] * scale;
      float m = fmaxf(fmaxf(v0, v1), fmaxf(v2, v3));
      for (int off = 8; off > 0; off >>= 1) m = fmaxf(m, __shfl_xor(m, off));
      float e0 = expf(v0 - m), e1 = expf(v1 - m), e2 = expf(v2 - m), e3 = expf(v3 - m);
      float s = e0 + e1 + e2 + e3;
      for (int off = 8; off > 0; off >>= 1) s += __shfl_xor(s, off);
      float inv = 1.f / s;
      accS[it][0][r] = e0 * inv; accS[it][1][r] = e1 * inv;
      accS[it][2][r] = e2 * inv; accS[it][3][r] = e3 * inv;
    }

  __syncthreads();

#pragma unroll
  for (int it = 0; it < 2; ++it)
#pragma unroll
    for (int jt = 0; jt < 4; ++jt)
#pragma unroll
      for (int r = 0; r < 4; ++r) {
        int row = wrow + it * 16 + (lg << 2) + r;
        int k = jt * 16 + lr;
        float p = accS[it][jt][r];
        bf16 ph = (bf16)p;
        int c = k >> 3;
        int off = (row * 8 + (c ^ (row & 7))) * 8 + (k & 7);
        sck[0][off] = ph;
        sck[1][off] = (bf16)(p - (float)ph);
      }
  __syncthreads();

  for (int half = 0; half < 2; ++half) {
    if (half) {
      __syncthreads();
      for (int idx = tid; idx < 512; idx += 256) {
        int d = idx >> 3, c = idx & 7;
        int dst = (d * 8 + (c ^ (d & 7))) * 8;
        *(uint4*)&sV[0][dst] = *(const uint4*)(gvh + (64 + d) * 64 + c * 8);
        *(uint4*)&sV[1][dst] = *(const uint4*)(gvl + (64 + d) * 64 + c * 8);
      }
      __syncthreads();
    }
    f32x4 accO[2][4] = {};
#pragma unroll
    for (int ks = 0; ks < 2; ++ks) {
      bf16x8 pah[2], pal[2], vh[4], vl[4];
#pragma unroll
      for (int it = 0; it < 2; ++it) {
        int row = wrow + it * 16 + lr;
        int c = ks * 4 + lg;
        int off = (row * 8 + (c ^ (row & 7))) * 8;
        pah[it] = *(const bf16x8*)&sck[0][off];
        pal[it] = *(const bf16x8*)&sck[1][off];
      }
#pragma unroll
      for (int jt = 0; jt < 4; ++jt) {
        int d = jt * 16 + lr;
        int c = ks * 4 + lg;
        int off = (d * 8 + (c ^ (d & 7))) * 8;
        vh[jt] = *(const bf16x8*)&sV[0][off];
        vl[jt] = *(const bf16x8*)&sV[1][off];
      }
#pragma unroll
      for (int it = 0; it < 2; ++it)
#pragma unroll
        for (int jt = 0; jt < 4; ++jt) {
          accO[it][jt] = __builtin_amdgcn_mfma_f32_16x16x32_bf16(pah[it], vh[jt], accO[it][jt], 0, 0, 0);
          accO[it][jt] = __builtin_amdgcn_mfma_f32_16x16x32_bf16(pah[it], vl[jt], accO[it][jt], 0, 0, 0);
          accO[it][jt] = __builtin_amdgcn_mfma_f32_16x16x32_bf16(pal[it], vh[jt], accO[it][jt], 0, 0, 0);
        }
    }
#pragma unroll
    for (int it = 0; it < 2; ++it)
#pragma unroll
      for (int jt = 0; jt < 4; ++jt)
#pragma unroll
        for (int r = 0; r < 4; ++r) {
          int row = wrow + it * 16 + (lg << 2) + r;
          int g = row0 + row;
          int t = g >> 2;
          int hh = kvh * NREP + (g & 3);
          size_t ob = (((size_t)b * TT + t) * NHQ + hh) * HD + half * 64 + jt * 16 + lr;
          float o = accO[it][jt][r];
          bf16 oh = (bf16)o;
          oh_g[ob] = oh;
          ol_g[ob] = (bf16)(o - (float)oh);
        }
  }
}

// ---------------- launch ----------------
extern "C" void kernel_launch(void* const* d_in, const int* in_sizes, int n_in,
                              void* d_out, int out_size, void* d_ws, size_t ws_size,
                              hipStream_t stream) {
  const float* x   = (const float*)d_in[0];
  const float* wq  = (const float*)d_in[1];
  const float* wk  = (const float*)d_in[2];
  const float* wv  = (const float*)d_in[3];
  const float* wo  = (const float*)d_in[4];
  const float* wiq = (const float*)d_in[5];
  const float* wik = (const float*)d_in[6];
  const float* cwa = (const float*)d_in[7];
  const float* cwb = (const float*)d_in[8];
  float* out = (float*)d_out;

  float* qb = out;  // q fp32 lives in d_out until the final GEMM overwrites it

  float* ws = (float*)d_ws;
  float* kb   = ws;
  float* vb   = kb + (size_t)MROWS * 512;
  bf16*  xh   = (bf16*)(vb + (size_t)MROWS * 512);
  bf16*  xl   = xh + XELE;
  bf16*  wqh  = xl + XELE;
  bf16*  wql  = wqh + (size_t)NQKV * CDIM;
  float* cost = (float*)(wql + (size_t)NQKV * CDIM);
  float* sint = cost + (size_t)TT * HALF;
  float* xpart = sint + (size_t)TT * HALF;
  float* ki   = xpart + (size_t)BB * 16 * CDIM;
  float* u    = ki + BB * HD;
  float* sc   = u + BB * CDIM;
  bf16*  ckh  = (bf16*)(sc + BB * NB);
  bf16*  ckl  = ckh + (size_t)BB * NKV * 64 * 128;
  bf16*  cvth = ckl + (size_t)BB * NKV * 64 * 128;
  bf16*  cvtl = cvth + (size_t)BB * NKV * 128 * 64;
  int* topk   = (int*)(cvtl + (size_t)BB * NKV * 128 * 64);
  bf16* oh  = xh;   // attention output hi/lo reuses xh/xl
  bf16* ol_ = xl;
  bf16* woh = wqh;  // wo^T hi/lo reuses wq^T region (converted after QKV GEMM)
  bf16* wol = wql;

  // 1. input conversions
  csa_xconv<<<(XELE / 4) / 256, 256, 0, stream>>>((const float4*)x, (bf16x4*)xh, (bf16x4*)xl);
  csa_wconv<<<dim3(CDIM / 32, CDIM / 32), 256, 0, stream>>>(wq, CDIM, wqh, wql, 0);
  csa_wconv<<<dim3(512 / 32, CDIM / 32), 256, 0, stream>>>(wk, 512, wqh, wql, CDIM);
  csa_wconv<<<dim3(512 / 32, CDIM / 32), 256, 0, stream>>>(wv, 512, wqh, wql, CDIM + 512);

  // 2. fused QKV projection (256x128 block tiles)
  csa_gemm_qkv<<<dim3(NQKV / 128, MROWS / 256), 256, 0, stream>>>(xh, xl, wqh, wql, qb, kb, vb);

  // 3. wo transpose+split (reuses wq^T region)
  csa_wconv<<<dim3(CDIM / 32, CDIM / 32), 256, 0, stream>>>(wo, CDIM, woh, wol, 0);

  // 4. RoPE table + apply to k only (q RoPE fused into attention)
  csa_rope_table<<<(TT * HALF + 255) / 256, 256, 0, stream>>>(cost, sint);
  csa_rope_apply<<<(BB * TT * NKV * HALF + 255) / 256, 256, 0, stream>>>(kb, cost, sint, NKV, BB * TT * NKV * HALF);

  // 5. selection
  csa_xpart<<<dim3(CDIM / 256, 16, BB), 256, 0, stream>>>(x, xpart);
  csa_kimean<<<BB * HD, 256, 0, stream>>>(xpart, wik, ki);
  csa_u<<<(BB * CDIM) / 256, 256, 0, stream>>>(wiq, ki, u);
  csa_scores<<<BB * NB, 256, 0, stream>>>(x, u, sc);
  csa_topk<<<BB, 256, 0, stream>>>(sc, topk);

  // 6. compress selected blocks -> split-bf16 MFMA layouts
  csa_compress<<<BB * NKV * TOPK, 64, 0, stream>>>(kb, vb, topk, cwa, cwb, ckh, ckl, cvth, cvtl);

  // 7. MFMA attention (fused q-RoPE) -> split-bf16 output
  csa_attn_mfma<<<dim3((TT * NREP) / 128, BB * NKV), 256, 0, stream>>>(qb, cost, sint, ckh, ckl, cvth, cvtl, oh, ol_);

  // 8. output projection (256x128 block tiles) -> d_out
  csa_gemm_wo<<<dim3(CDIM / 128, MROWS / 256), 256, 0, stream>>>(oh, ol_, woh, wol, out);
}